// Round 2
// baseline (699.352 us; speedup 1.0000x reference)
//
#include <hip/hip_runtime.h>
#include <stdint.h>

static constexpr int BATCH  = 8;
static constexpr int SEQ    = 1024;
static constexpr int DMODEL = 1024;
static constexpr int NHEAD  = 16;

typedef __attribute__((ext_vector_type(8))) short sh8;
typedef __attribute__((ext_vector_type(4))) float fl4;

__device__ __forceinline__ uint16_t f2bf(float f) {
    union { float f; uint32_t u; } a; a.f = f;
    uint32_t r = a.u + 0x7FFFu + ((a.u >> 16) & 1u);
    return (uint16_t)(r >> 16);
}

__device__ __forceinline__ sh8 pack_bf8(fl4 x0, fl4 x1) {
    union { uint16_t u[8]; sh8 v; } pk;
    pk.u[0] = f2bf(x0[0]); pk.u[1] = f2bf(x0[1]); pk.u[2] = f2bf(x0[2]); pk.u[3] = f2bf(x0[3]);
    pk.u[4] = f2bf(x1[0]); pk.u[5] = f2bf(x1[1]); pk.u[6] = f2bf(x1[2]); pk.u[7] = f2bf(x1[3]);
    return pk.v;
}

__device__ __forceinline__ fl4 mfma16(sh8 a, sh8 b, fl4 c) {
    return __builtin_amdgcn_mfma_f32_16x16x32_bf16(a, b, c, 0, 0, 0);
}

// ---------------- weight transpose + fp32->bf16 convert: wT[n][k] = w[k][n]
__global__ __launch_bounds__(256) void wtrans_kernel(const float* __restrict__ w,
                                                     uint16_t* __restrict__ wT) {
    __shared__ uint16_t T[64][72];
    const int n0 = blockIdx.x * 64, k0 = blockIdx.y * 64;
    const int tid = threadIdx.x;
    #pragma unroll
    for (int it = 0; it < 4; ++it) {
        int g = it * 256 + tid;
        int r = g >> 4, c = (g & 15) * 4;
        fl4 x = *(const fl4*)(w + (size_t)(k0 + r) * DMODEL + n0 + c);
        T[r][c + 0] = f2bf(x[0]); T[r][c + 1] = f2bf(x[1]);
        T[r][c + 2] = f2bf(x[2]); T[r][c + 3] = f2bf(x[3]);
    }
    __syncthreads();
    #pragma unroll
    for (int it = 0; it < 4; ++it) {
        int g = it * 256 + tid;
        int r = g >> 4, c = (g & 15) * 4;
        ushort4 o;
        o.x = T[c + 0][r]; o.y = T[c + 1][r]; o.z = T[c + 2][r]; o.w = T[c + 3][r];
        *(ushort4*)(wT + (size_t)(n0 + r) * DMODEL + k0 + c) = o;
    }
}

// ---------------- per-batch 1024x1024 bf16 transpose: vT[b*1024+hd][l] = vh[b*1024+l][hd]
__global__ __launch_bounds__(256) void vtrans_kernel(const uint16_t* __restrict__ vh,
                                                     uint16_t* __restrict__ vT) {
    __shared__ uint16_t T[64][72];
    const int l0 = blockIdx.x * 64, hd0 = blockIdx.y * 64, bb = blockIdx.z;
    const uint16_t* src = vh + (size_t)bb * SEQ * DMODEL;
    uint16_t* dst = vT + (size_t)bb * SEQ * DMODEL;
    const int tid = threadIdx.x;
    #pragma unroll
    for (int it = 0; it < 4; ++it) {
        int g = it * 256 + tid;
        int r = g >> 4, c = (g & 15) * 4;
        ushort4 x = *(const ushort4*)(src + (size_t)(l0 + r) * DMODEL + hd0 + c);
        T[r][c + 0] = x.x; T[r][c + 1] = x.y; T[r][c + 2] = x.z; T[r][c + 3] = x.w;
    }
    __syncthreads();
    #pragma unroll
    for (int it = 0; it < 4; ++it) {
        int g = it * 256 + tid;
        int r = g >> 4, c = (g & 15) * 4;
        ushort4 o;
        o.x = T[c + 0][r]; o.y = T[c + 1][r]; o.z = T[c + 2][r]; o.w = T[c + 3][r];
        *(ushort4*)(dst + (size_t)(hd0 + r) * DMODEL + l0 + c) = o;
    }
}

// ---------------- GEMM: C[8192,1024] = A[8192,1024] * Bt[1024(n),1024(k)]^T + bias (+resid)
template<bool A_F32, bool OUT_BF16, bool RESID>
__global__ __launch_bounds__(256)
void gemm128(const void* __restrict__ Av, const uint16_t* __restrict__ Bt,
             const float* __restrict__ bias, const float* __restrict__ resid,
             void* __restrict__ Cv) {
    __shared__ uint16_t Alds[128 * 64];
    __shared__ uint16_t Blds[128 * 64];
    const int tid = threadIdx.x;
    const int m0 = blockIdx.y * 128, n0 = blockIdx.x * 128;
    const int lane = tid & 63, wid = tid >> 6;
    const int wr = (wid >> 1) * 64, wc = (wid & 1) * 64;
    const int fr = lane & 15, fk = (lane >> 4) * 8;

    fl4 acc[4][4];
    #pragma unroll
    for (int i = 0; i < 4; ++i)
        #pragma unroll
        for (int j = 0; j < 4; ++j) acc[i][j] = (fl4){0.f, 0.f, 0.f, 0.f};

    const float* Af = (const float*)Av;
    const uint16_t* Ab = (const uint16_t*)Av;

    for (int kt = 0; kt < 16; ++kt) {
        const int kb = kt * 64;
        #pragma unroll
        for (int it = 0; it < 4; ++it) {
            int g = it * 256 + tid;
            int r = g >> 3, c = (g & 7) << 3;
            if (A_F32) {
                const float* p = Af + (size_t)(m0 + r) * DMODEL + kb + c;
                fl4 x0 = *(const fl4*)p, x1 = *(const fl4*)(p + 4);
                *(sh8*)&Alds[r * 64 + c] = pack_bf8(x0, x1);
            } else {
                *(sh8*)&Alds[r * 64 + c] = *(const sh8*)(Ab + (size_t)(m0 + r) * DMODEL + kb + c);
            }
            *(sh8*)&Blds[r * 64 + c] = *(const sh8*)(Bt + (size_t)(n0 + r) * DMODEL + kb + c);
        }
        __syncthreads();
        #pragma unroll
        for (int ks = 0; ks < 2; ++ks) {
            sh8 a[4], bb[4];
            #pragma unroll
            for (int mi = 0; mi < 4; ++mi) a[mi] = *(const sh8*)&Alds[(wr + mi * 16 + fr) * 64 + ks * 32 + fk];
            #pragma unroll
            for (int ni = 0; ni < 4; ++ni) bb[ni] = *(const sh8*)&Blds[(wc + ni * 16 + fr) * 64 + ks * 32 + fk];
            #pragma unroll
            for (int mi = 0; mi < 4; ++mi)
                #pragma unroll
                for (int ni = 0; ni < 4; ++ni) acc[mi][ni] = mfma16(a[mi], bb[ni], acc[mi][ni]);
        }
        __syncthreads();
    }

    #pragma unroll
    for (int mi = 0; mi < 4; ++mi) {
        #pragma unroll
        for (int ni = 0; ni < 4; ++ni) {
            const int col = n0 + wc + ni * 16 + fr;
            const float bv = bias[col];
            #pragma unroll
            for (int i = 0; i < 4; ++i) {
                const int row = m0 + wr + mi * 16 + (lane >> 4) * 4 + i;
                float val = acc[mi][ni][i] + bv;
                if (RESID) val += resid[(size_t)row * DMODEL + col];
                if (OUT_BF16) ((uint16_t*)Cv)[(size_t)row * DMODEL + col] = f2bf(val);
                else          ((float*)Cv)[(size_t)row * DMODEL + col] = val;
            }
        }
    }
}

// ---------------- attention: one block = (b, h, 16 q-rows); S[16][1024] fp32 in static LDS (64KB)
__global__ __launch_bounds__(256)
void attn_kernel(const uint16_t* __restrict__ qh, const uint16_t* __restrict__ kh,
                 const uint16_t* __restrict__ vT, const unsigned char* __restrict__ mask,
                 float* __restrict__ attn, uint16_t* __restrict__ ctx) {
    __shared__ float S[16 * SEQ];           // exactly 65536 bytes
    const int q0 = blockIdx.x * 16, h = blockIdx.y, b = blockIdx.z;
    const int tid = threadIdx.x, lane = tid & 63, wid = tid >> 6;
    const int fr = lane & 15, fk = (lane >> 4) * 8, frow4 = (lane >> 4) * 4;

    // Q fragments (16x64 tile, each wave holds full copy)
    sh8 Aq[2];
    #pragma unroll
    for (int ks = 0; ks < 2; ++ks)
        Aq[ks] = *(const sh8*)(qh + (size_t)(b * SEQ + q0 + fr) * DMODEL + h * 64 + ks * 32 + fk);

    // phase 1: S = (Q K^T) * 0.125 ; wave wid covers kv tiles {wid, wid+4, ...}
    for (int t8 = 0; t8 < 8; ++t8) {
        const int kv0 = (t8 * 4 + wid) * 32;
        sh8 Bk[2][2];
        #pragma unroll
        for (int ni = 0; ni < 2; ++ni)
            #pragma unroll
            for (int ks = 0; ks < 2; ++ks)
                Bk[ni][ks] = *(const sh8*)(kh + (size_t)(b * SEQ + kv0 + ni * 16 + fr) * DMODEL + h * 64 + ks * 32 + fk);
        fl4 sa[2];
        #pragma unroll
        for (int ni = 0; ni < 2; ++ni) sa[ni] = (fl4){0.f, 0.f, 0.f, 0.f};
        #pragma unroll
        for (int ni = 0; ni < 2; ++ni)
            #pragma unroll
            for (int ks = 0; ks < 2; ++ks) sa[ni] = mfma16(Aq[ks], Bk[ni][ks], sa[ni]);
        #pragma unroll
        for (int ni = 0; ni < 2; ++ni)
            #pragma unroll
            for (int i = 0; i < 4; ++i)
                S[(frow4 + i) * SEQ + kv0 + ni * 16 + fr] = sa[ni][i] * 0.125f;
    }
    __syncthreads();

    // phase 2: masked softmax with fused normalization; 16 lanes per row, 64 cols each
    {
        const int r = tid >> 4, j = tid & 15;
        float* Srow = S + r * SEQ + j * 64;
        const uint32_t* m32 = (const uint32_t*)(mask + (size_t)(b * SEQ + q0 + r) * SEQ + j * 64);
        float mx = -1e30f;
        #pragma unroll
        for (int c4 = 0; c4 < 16; ++c4) {
            uint32_t mw = m32[c4];
            fl4 s4 = *(fl4*)&Srow[c4 * 4];
            if (mw & 0x000000FFu) s4[0] = -1e9f;
            if (mw & 0x0000FF00u) s4[1] = -1e9f;
            if (mw & 0x00FF0000u) s4[2] = -1e9f;
            if (mw & 0xFF000000u) s4[3] = -1e9f;
            *(fl4*)&Srow[c4 * 4] = s4;
            mx = fmaxf(mx, fmaxf(fmaxf(s4[0], s4[1]), fmaxf(s4[2], s4[3])));
        }
        #pragma unroll
        for (int d = 1; d < 16; d <<= 1) mx = fmaxf(mx, __shfl_xor(mx, d));
        float sum = 0.f;
        #pragma unroll
        for (int c4 = 0; c4 < 16; ++c4) {
            fl4 s4 = *(fl4*)&Srow[c4 * 4];
            fl4 e;
            #pragma unroll
            for (int jj = 0; jj < 4; ++jj) e[jj] = __expf(s4[jj] - mx);
            *(fl4*)&Srow[c4 * 4] = e;
            sum += e[0] + e[1] + e[2] + e[3];
        }
        #pragma unroll
        for (int d = 1; d < 16; d <<= 1) sum += __shfl_xor(sum, d);
        const float rinv = 1.f / sum;
        #pragma unroll
        for (int c4 = 0; c4 < 16; ++c4) {
            fl4 e = *(fl4*)&Srow[c4 * 4];
            #pragma unroll
            for (int jj = 0; jj < 4; ++jj) e[jj] *= rinv;
            *(fl4*)&Srow[c4 * 4] = e;
        }
    }
    __syncthreads();

    // phase 2c: coalesced attn global write (S already normalized)
    {
        float* ab = attn + ((size_t)((h * BATCH + b) * SEQ + q0)) * SEQ;
        #pragma unroll
        for (int it = 0; it < 64; ++it) {
            int idx = it * 256 + tid;
            ab[idx] = S[idx];
        }
    }

    // phase 3: ctx = P V ; K=1024 split across 4 waves (256 each)
    fl4 cacc[4];
    #pragma unroll
    for (int ni = 0; ni < 4; ++ni) cacc[ni] = (fl4){0.f, 0.f, 0.f, 0.f};
    const uint16_t* vbase = vT + (size_t)((b * NHEAD + h) * 64) * SEQ;
    for (int t8 = 0; t8 < 8; ++t8) {
        const int kv0 = wid * 256 + t8 * 32;
        sh8 Ap;
        {
            const float* sp = S + (size_t)fr * SEQ + kv0 + fk;
            fl4 x0 = *(const fl4*)sp, x1 = *(const fl4*)(sp + 4);
            Ap = pack_bf8(x0, x1);
        }
        sh8 Bv[4];
        #pragma unroll
        for (int ni = 0; ni < 4; ++ni)
            Bv[ni] = *(const sh8*)(vbase + (size_t)(ni * 16 + fr) * SEQ + kv0 + fk);
        #pragma unroll
        for (int ni = 0; ni < 4; ++ni) cacc[ni] = mfma16(Ap, Bv[ni], cacc[ni]);
    }
    __syncthreads();
    // partials into reused S region: [wid][16][64]
    #pragma unroll
    for (int ni = 0; ni < 4; ++ni)
        #pragma unroll
        for (int i = 0; i < 4; ++i)
            S[wid * 1024 + (frow4 + i) * 64 + ni * 16 + fr] = cacc[ni][i];
    __syncthreads();
    #pragma unroll
    for (int it = 0; it < 4; ++it) {
        int idx = it * 256 + tid;
        float v = S[idx] + S[1024 + idx] + S[2048 + idx] + S[3072 + idx];
        int rr = idx >> 6, cc = idx & 63;
        ctx[(size_t)(b * SEQ + q0 + rr) * DMODEL + h * 64 + cc] = f2bf(v);
    }
}

// ---------------- LayerNorm (in-place capable): one block per row
__global__ __launch_bounds__(256)
void ln_kernel(const float* __restrict__ raw, const float* __restrict__ gamma,
               const float* __restrict__ beta, float* __restrict__ out) {
    const int row = blockIdx.x;
    const int tid = threadIdx.x;
    const float* x = raw + (size_t)row * DMODEL;
    fl4 xv = *(const fl4*)(x + tid * 4);
    float s  = xv[0] + xv[1] + xv[2] + xv[3];
    float ss = xv[0] * xv[0] + xv[1] * xv[1] + xv[2] * xv[2] + xv[3] * xv[3];
    #pragma unroll
    for (int d = 1; d < 64; d <<= 1) { s += __shfl_xor(s, d); ss += __shfl_xor(ss, d); }
    __shared__ float sb[4], ssb[4];
    if ((tid & 63) == 0) { sb[tid >> 6] = s; ssb[tid >> 6] = ss; }
    __syncthreads();
    s  = sb[0] + sb[1] + sb[2] + sb[3];
    ss = ssb[0] + ssb[1] + ssb[2] + ssb[3];
    const float mu  = s * (1.f / 1024.f);
    const float var = ss * (1.f / 1024.f) - mu * mu;
    const float rstd = rsqrtf(var + 1e-5f);
    fl4 g  = *(const fl4*)(gamma + tid * 4);
    fl4 be = *(const fl4*)(beta + tid * 4);
    fl4 o;
    #pragma unroll
    for (int j = 0; j < 4; ++j) o[j] = (xv[j] - mu) * rstd * g[j] + be[j];
    *(fl4*)(out + (size_t)row * DMODEL + tid * 4) = o;
}

extern "C" void kernel_launch(void* const* d_in, const int* in_sizes, int n_in,
                              void* d_out, int out_size, void* d_ws, size_t ws_size,
                              hipStream_t stream) {
    (void)in_sizes; (void)n_in; (void)out_size; (void)ws_size;
    const float* q     = (const float*)d_in[0];
    const float* k     = (const float*)d_in[1];
    const float* v     = (const float*)d_in[2];
    const unsigned char* mask = (const unsigned char*)d_in[3];
    const float* wq = (const float*)d_in[4];
    const float* bq = (const float*)d_in[5];
    const float* wk = (const float*)d_in[6];
    const float* bk = (const float*)d_in[7];
    const float* wv = (const float*)d_in[8];
    const float* bv = (const float*)d_in[9];
    const float* wo = (const float*)d_in[10];
    const float* bo = (const float*)d_in[11];
    const float* gamma = (const float*)d_in[12];
    const float* beta  = (const float*)d_in[13];

    float* out  = (float*)d_out;                                   // 8M fp32 (raw out-proj, then LN in-place)
    float* attn = out + (size_t)BATCH * SEQ * DMODEL;              // 128M fp32

    char* ws = (char*)d_ws;
    uint16_t* qh   = (uint16_t*)(ws);                              // 16 MB
    uint16_t* kh   = (uint16_t*)(ws + ((size_t)16 << 20));         // 16 MB
    uint16_t* vT   = (uint16_t*)(ws + ((size_t)32 << 20));         // 16 MB
    uint16_t* ctx  = (uint16_t*)(ws + ((size_t)48 << 20));         // 16 MB
    uint16_t* wqT  = (uint16_t*)(ws + ((size_t)64 << 20));         // 2 MB each
    uint16_t* wkT  = (uint16_t*)(ws + ((size_t)66 << 20));
    uint16_t* wvT  = (uint16_t*)(ws + ((size_t)68 << 20));
    uint16_t* woT  = (uint16_t*)(ws + ((size_t)70 << 20));
    uint16_t* vtmp = (uint16_t*)(ws + ((size_t)72 << 20));         // 16 MB -> total 88 MB

    dim3 tb(256);
    wtrans_kernel<<<dim3(16, 16), tb, 0, stream>>>(wq, wqT);
    wtrans_kernel<<<dim3(16, 16), tb, 0, stream>>>(wk, wkT);
    wtrans_kernel<<<dim3(16, 16), tb, 0, stream>>>(wv, wvT);
    wtrans_kernel<<<dim3(16, 16), tb, 0, stream>>>(wo, woT);

    gemm128<true, true, false><<<dim3(8, 64), tb, 0, stream>>>(q, wqT, bq, nullptr, qh);
    gemm128<true, true, false><<<dim3(8, 64), tb, 0, stream>>>(k, wkT, bk, nullptr, kh);
    gemm128<true, true, false><<<dim3(8, 64), tb, 0, stream>>>(v, wvT, bv, nullptr, vtmp);

    vtrans_kernel<<<dim3(16, 16, 8), tb, 0, stream>>>(vtmp, vT);

    attn_kernel<<<dim3(64, NHEAD, BATCH), tb, 0, stream>>>(qh, kh, vT, mask, attn, ctx);

    gemm128<false, false, true><<<dim3(8, 64), tb, 0, stream>>>(ctx, woT, bo, q, out);

    ln_kernel<<<BATCH * SEQ, tb, 0, stream>>>(out, gamma, beta, out);
}

// Round 3
// 572.470 us; speedup vs baseline: 1.2216x; 1.2216x over previous
//
#include <hip/hip_runtime.h>
#include <stdint.h>

static constexpr int BATCH  = 8;
static constexpr int SEQ    = 1024;
static constexpr int DMODEL = 1024;
static constexpr int NHEAD  = 16;

typedef __attribute__((ext_vector_type(8))) short sh8;
typedef __attribute__((ext_vector_type(4))) float fl4;

__device__ __forceinline__ uint16_t f2bf(float f) {
    union { float f; uint32_t u; } a; a.f = f;
    uint32_t r = a.u + 0x7FFFu + ((a.u >> 16) & 1u);
    return (uint16_t)(r >> 16);
}

__device__ __forceinline__ sh8 pack_bf8(fl4 x0, fl4 x1) {
    union { uint16_t u[8]; sh8 v; } pk;
    pk.u[0] = f2bf(x0[0]); pk.u[1] = f2bf(x0[1]); pk.u[2] = f2bf(x0[2]); pk.u[3] = f2bf(x0[3]);
    pk.u[4] = f2bf(x1[0]); pk.u[5] = f2bf(x1[1]); pk.u[6] = f2bf(x1[2]); pk.u[7] = f2bf(x1[3]);
    return pk.v;
}

__device__ __forceinline__ fl4 mfma16(sh8 a, sh8 b, fl4 c) {
    return __builtin_amdgcn_mfma_f32_16x16x32_bf16(a, b, c, 0, 0, 0);
}

// S swizzle: float index for (row, fl4-chunk c). chunk' = c ^ (row&7) breaks the
// 4096B row stride (all rows bank-0) AND the 64-float column-block stride.
__device__ __forceinline__ int swc(int row, int c) {
    return row * 1024 + (((c ^ (row & 7)) << 2));
}

// ---------------- weight transpose + fp32->bf16 convert: wT[n][k] = w[k][n]
__global__ __launch_bounds__(256) void wtrans_kernel(const float* __restrict__ w,
                                                     uint16_t* __restrict__ wT) {
    __shared__ uint16_t T[64][72];
    const int n0 = blockIdx.x * 64, k0 = blockIdx.y * 64;
    const int tid = threadIdx.x;
    #pragma unroll
    for (int it = 0; it < 4; ++it) {
        int g = it * 256 + tid;
        int r = g >> 4, c = (g & 15) * 4;
        fl4 x = *(const fl4*)(w + (size_t)(k0 + r) * DMODEL + n0 + c);
        T[r][c + 0] = f2bf(x[0]); T[r][c + 1] = f2bf(x[1]);
        T[r][c + 2] = f2bf(x[2]); T[r][c + 3] = f2bf(x[3]);
    }
    __syncthreads();
    #pragma unroll
    for (int it = 0; it < 4; ++it) {
        int g = it * 256 + tid;
        int r = g >> 4, c = (g & 15) * 4;
        ushort4 o;
        o.x = T[c + 0][r]; o.y = T[c + 1][r]; o.z = T[c + 2][r]; o.w = T[c + 3][r];
        *(ushort4*)(wT + (size_t)(n0 + r) * DMODEL + k0 + c) = o;
    }
}

// ---------------- per-batch 1024x1024 bf16 transpose: vT[b*1024+hd][l] = vh[b*1024+l][hd]
__global__ __launch_bounds__(256) void vtrans_kernel(const uint16_t* __restrict__ vh,
                                                     uint16_t* __restrict__ vT) {
    __shared__ uint16_t T[64][72];
    const int l0 = blockIdx.x * 64, hd0 = blockIdx.y * 64, bb = blockIdx.z;
    const uint16_t* src = vh + (size_t)bb * SEQ * DMODEL;
    uint16_t* dst = vT + (size_t)bb * SEQ * DMODEL;
    const int tid = threadIdx.x;
    #pragma unroll
    for (int it = 0; it < 4; ++it) {
        int g = it * 256 + tid;
        int r = g >> 4, c = (g & 15) * 4;
        ushort4 x = *(const ushort4*)(src + (size_t)(l0 + r) * DMODEL + hd0 + c);
        T[r][c + 0] = x.x; T[r][c + 1] = x.y; T[r][c + 2] = x.z; T[r][c + 3] = x.w;
    }
    __syncthreads();
    #pragma unroll
    for (int it = 0; it < 4; ++it) {
        int g = it * 256 + tid;
        int r = g >> 4, c = (g & 15) * 4;
        ushort4 o;
        o.x = T[c + 0][r]; o.y = T[c + 1][r]; o.z = T[c + 2][r]; o.w = T[c + 3][r];
        *(ushort4*)(dst + (size_t)(hd0 + r) * DMODEL + l0 + c) = o;
    }
}

// ---------------- GEMM: C[8192,1024] = A[8192,1024] * Bt[1024(n),1024(k)]^T + bias (+resid)
template<bool A_F32, bool OUT_BF16, bool RESID>
__global__ __launch_bounds__(256)
void gemm128(const void* __restrict__ Av, const uint16_t* __restrict__ Bt,
             const float* __restrict__ bias, const float* __restrict__ resid,
             void* __restrict__ Cv) {
    __shared__ uint16_t Alds[128 * 64];
    __shared__ uint16_t Blds[128 * 64];
    const int tid = threadIdx.x;
    const int m0 = blockIdx.y * 128, n0 = blockIdx.x * 128;
    const int lane = tid & 63, wid = tid >> 6;
    const int wr = (wid >> 1) * 64, wc = (wid & 1) * 64;
    const int fr = lane & 15, fk = (lane >> 4) * 8;

    fl4 acc[4][4];
    #pragma unroll
    for (int i = 0; i < 4; ++i)
        #pragma unroll
        for (int j = 0; j < 4; ++j) acc[i][j] = (fl4){0.f, 0.f, 0.f, 0.f};

    const float* Af = (const float*)Av;
    const uint16_t* Ab = (const uint16_t*)Av;

    for (int kt = 0; kt < 16; ++kt) {
        const int kb = kt * 64;
        #pragma unroll
        for (int it = 0; it < 4; ++it) {
            int g = it * 256 + tid;
            int r = g >> 3, c = (g & 7) << 3;
            if (A_F32) {
                const float* p = Af + (size_t)(m0 + r) * DMODEL + kb + c;
                fl4 x0 = *(const fl4*)p, x1 = *(const fl4*)(p + 4);
                *(sh8*)&Alds[r * 64 + c] = pack_bf8(x0, x1);
            } else {
                *(sh8*)&Alds[r * 64 + c] = *(const sh8*)(Ab + (size_t)(m0 + r) * DMODEL + kb + c);
            }
            *(sh8*)&Blds[r * 64 + c] = *(const sh8*)(Bt + (size_t)(n0 + r) * DMODEL + kb + c);
        }
        __syncthreads();
        #pragma unroll
        for (int ks = 0; ks < 2; ++ks) {
            sh8 a[4], bb[4];
            #pragma unroll
            for (int mi = 0; mi < 4; ++mi) a[mi] = *(const sh8*)&Alds[(wr + mi * 16 + fr) * 64 + ks * 32 + fk];
            #pragma unroll
            for (int ni = 0; ni < 4; ++ni) bb[ni] = *(const sh8*)&Blds[(wc + ni * 16 + fr) * 64 + ks * 32 + fk];
            #pragma unroll
            for (int mi = 0; mi < 4; ++mi)
                #pragma unroll
                for (int ni = 0; ni < 4; ++ni) acc[mi][ni] = mfma16(a[mi], bb[ni], acc[mi][ni]);
        }
        __syncthreads();
    }

    #pragma unroll
    for (int mi = 0; mi < 4; ++mi) {
        #pragma unroll
        for (int ni = 0; ni < 4; ++ni) {
            const int col = n0 + wc + ni * 16 + fr;
            const float bv = bias[col];
            #pragma unroll
            for (int i = 0; i < 4; ++i) {
                const int row = m0 + wr + mi * 16 + (lane >> 4) * 4 + i;
                float val = acc[mi][ni][i] + bv;
                if (RESID) val += resid[(size_t)row * DMODEL + col];
                if (OUT_BF16) ((uint16_t*)Cv)[(size_t)row * DMODEL + col] = f2bf(val);
                else          ((float*)Cv)[(size_t)row * DMODEL + col] = val;
            }
        }
    }
}

// ---------------- attention: one block = (b, h, 16 q-rows); S[16][1024] fp32, XOR-swizzled
__global__ __launch_bounds__(256)
void attn_kernel(const uint16_t* __restrict__ qh, const uint16_t* __restrict__ kh,
                 const uint16_t* __restrict__ vT, const unsigned char* __restrict__ mask,
                 float* __restrict__ attn, uint16_t* __restrict__ ctx) {
    __shared__ float S[16 * SEQ];           // exactly 65536 bytes
    const int q0 = blockIdx.x * 16, h = blockIdx.y, b = blockIdx.z;
    const int tid = threadIdx.x, lane = tid & 63, wid = tid >> 6;
    const int fr = lane & 15, fk = (lane >> 4) * 8, frow4 = (lane >> 4) * 4;

    // Q fragments (16x64 tile, each wave holds full copy)
    sh8 Aq[2];
    #pragma unroll
    for (int ks = 0; ks < 2; ++ks)
        Aq[ks] = *(const sh8*)(qh + (size_t)(b * SEQ + q0 + fr) * DMODEL + h * 64 + ks * 32 + fk);

    // phase 1: S = (Q K^T) * 0.125 ; wave wid covers kv tiles {wid, wid+4, ...}
    for (int t8 = 0; t8 < 8; ++t8) {
        const int kv0 = (t8 * 4 + wid) * 32;
        sh8 Bk[2][2];
        #pragma unroll
        for (int ni = 0; ni < 2; ++ni)
            #pragma unroll
            for (int ks = 0; ks < 2; ++ks)
                Bk[ni][ks] = *(const sh8*)(kh + (size_t)(b * SEQ + kv0 + ni * 16 + fr) * DMODEL + h * 64 + ks * 32 + fk);
        fl4 sa[2];
        #pragma unroll
        for (int ni = 0; ni < 2; ++ni) sa[ni] = (fl4){0.f, 0.f, 0.f, 0.f};
        #pragma unroll
        for (int ni = 0; ni < 2; ++ni)
            #pragma unroll
            for (int ks = 0; ks < 2; ++ks) sa[ni] = mfma16(Aq[ks], Bk[ni][ks], sa[ni]);
        #pragma unroll
        for (int ni = 0; ni < 2; ++ni)
            #pragma unroll
            for (int i = 0; i < 4; ++i) {
                const int row = frow4 + i, col = kv0 + ni * 16 + fr;
                S[swc(row, col >> 2) + (col & 3)] = sa[ni][i] * 0.125f;
            }
    }
    __syncthreads();

    // phase 2: masked softmax + normalization; 16 lanes/row, interleaved fl4 chunks
    {
        const int r = tid >> 4, j = tid & 15;
        const uint32_t* m32 = (const uint32_t*)(mask + (size_t)(b * SEQ + q0 + r) * SEQ);
        float mx = -1e30f;
        #pragma unroll
        for (int c4 = 0; c4 < 16; ++c4) {
            const int cc = c4 * 16 + j;
            uint32_t mw = m32[cc];
            fl4 s4 = *(fl4*)&S[swc(r, cc)];
            if (mw & 0x000000FFu) s4[0] = -1e9f;
            if (mw & 0x0000FF00u) s4[1] = -1e9f;
            if (mw & 0x00FF0000u) s4[2] = -1e9f;
            if (mw & 0xFF000000u) s4[3] = -1e9f;
            *(fl4*)&S[swc(r, cc)] = s4;
            mx = fmaxf(mx, fmaxf(fmaxf(s4[0], s4[1]), fmaxf(s4[2], s4[3])));
        }
        #pragma unroll
        for (int d = 1; d < 16; d <<= 1) mx = fmaxf(mx, __shfl_xor(mx, d));
        float sum = 0.f;
        #pragma unroll
        for (int c4 = 0; c4 < 16; ++c4) {
            const int cc = c4 * 16 + j;
            fl4 s4 = *(fl4*)&S[swc(r, cc)];
            fl4 e;
            #pragma unroll
            for (int jj = 0; jj < 4; ++jj) e[jj] = __expf(s4[jj] - mx);
            *(fl4*)&S[swc(r, cc)] = e;
            sum += e[0] + e[1] + e[2] + e[3];
        }
        #pragma unroll
        for (int d = 1; d < 16; d <<= 1) sum += __shfl_xor(sum, d);
        const float rinv = 1.f / sum;
        #pragma unroll
        for (int c4 = 0; c4 < 16; ++c4) {
            const int cc = c4 * 16 + j;
            fl4 e = *(fl4*)&S[swc(r, cc)];
            #pragma unroll
            for (int jj = 0; jj < 4; ++jj) e[jj] *= rinv;
            *(fl4*)&S[swc(r, cc)] = e;
        }
    }
    __syncthreads();

    // phase 2c: coalesced fl4 attn global write (S already normalized)
    {
        fl4* ab4 = (fl4*)(attn + ((size_t)((h * BATCH + b) * SEQ + q0)) * SEQ);
        #pragma unroll
        for (int it = 0; it < 16; ++it) {
            int ch = it * 256 + tid;            // fl4 chunk id over 16x256
            int row = ch >> 8, cc = ch & 255;
            ab4[ch] = *(fl4*)&S[swc(row, cc)];
        }
    }

    // phase 3: ctx = P V ; K=1024 split across 4 waves (256 each)
    fl4 cacc[4];
    #pragma unroll
    for (int ni = 0; ni < 4; ++ni) cacc[ni] = (fl4){0.f, 0.f, 0.f, 0.f};
    const uint16_t* vbase = vT + (size_t)((b * NHEAD + h) * 64) * SEQ;
    for (int t8 = 0; t8 < 8; ++t8) {
        const int kv0 = wid * 256 + t8 * 32;
        const int cc0 = (kv0 + fk) >> 2;
        sh8 Ap;
        {
            fl4 x0 = *(const fl4*)&S[swc(fr, cc0)];
            fl4 x1 = *(const fl4*)&S[swc(fr, cc0 + 1)];
            Ap = pack_bf8(x0, x1);
        }
        sh8 Bv[4];
        #pragma unroll
        for (int ni = 0; ni < 4; ++ni)
            Bv[ni] = *(const sh8*)(vbase + (size_t)(ni * 16 + fr) * SEQ + kv0 + fk);
        #pragma unroll
        for (int ni = 0; ni < 4; ++ni) cacc[ni] = mfma16(Ap, Bv[ni], cacc[ni]);
    }
    __syncthreads();
    // partials into reused S region: wave wid owns floats [wid*1024, wid*1024+1024)
    // logical (p,row 0..15; col 0..63), chunk-swizzled like main S (chunk space 0..15)
    #pragma unroll
    for (int ni = 0; ni < 4; ++ni)
        #pragma unroll
        for (int i = 0; i < 4; ++i) {
            const int p = frow4 + i, col = ni * 16 + fr;
            S[wid * 1024 + p * 64 + (((col >> 2) ^ (p & 7)) << 2) + (col & 3)] = cacc[ni][i];
        }
    __syncthreads();
    #pragma unroll
    for (int it = 0; it < 4; ++it) {
        int idx = it * 256 + tid;
        int rr = idx >> 6, cc = idx & 63;
        int off = rr * 64 + (((cc >> 2) ^ (rr & 7)) << 2) + (cc & 3);
        float v = S[off] + S[1024 + off] + S[2048 + off] + S[3072 + off];
        ctx[(size_t)(b * SEQ + q0 + rr) * DMODEL + h * 64 + cc] = f2bf(v);
    }
}

// ---------------- LayerNorm (in-place capable): one block per row
__global__ __launch_bounds__(256)
void ln_kernel(const float* __restrict__ raw, const float* __restrict__ gamma,
               const float* __restrict__ beta, float* __restrict__ out) {
    const int row = blockIdx.x;
    const int tid = threadIdx.x;
    const float* x = raw + (size_t)row * DMODEL;
    fl4 xv = *(const fl4*)(x + tid * 4);
    float s  = xv[0] + xv[1] + xv[2] + xv[3];
    float ss = xv[0] * xv[0] + xv[1] * xv[1] + xv[2] * xv[2] + xv[3] * xv[3];
    #pragma unroll
    for (int d = 1; d < 64; d <<= 1) { s += __shfl_xor(s, d); ss += __shfl_xor(ss, d); }
    __shared__ float sb[4], ssb[4];
    if ((tid & 63) == 0) { sb[tid >> 6] = s; ssb[tid >> 6] = ss; }
    __syncthreads();
    s  = sb[0] + sb[1] + sb[2] + sb[3];
    ss = ssb[0] + ssb[1] + ssb[2] + ssb[3];
    const float mu  = s * (1.f / 1024.f);
    const float var = ss * (1.f / 1024.f) - mu * mu;
    const float rstd = rsqrtf(var + 1e-5f);
    fl4 g  = *(const fl4*)(gamma + tid * 4);
    fl4 be = *(const fl4*)(beta + tid * 4);
    fl4 o;
    #pragma unroll
    for (int j = 0; j < 4; ++j) o[j] = (xv[j] - mu) * rstd * g[j] + be[j];
    *(fl4*)(out + (size_t)row * DMODEL + tid * 4) = o;
}

extern "C" void kernel_launch(void* const* d_in, const int* in_sizes, int n_in,
                              void* d_out, int out_size, void* d_ws, size_t ws_size,
                              hipStream_t stream) {
    (void)in_sizes; (void)n_in; (void)out_size; (void)ws_size;
    const float* q     = (const float*)d_in[0];
    const float* k     = (const float*)d_in[1];
    const float* v     = (const float*)d_in[2];
    const unsigned char* mask = (const unsigned char*)d_in[3];
    const float* wq = (const float*)d_in[4];
    const float* bq = (const float*)d_in[5];
    const float* wk = (const float*)d_in[6];
    const float* bk = (const float*)d_in[7];
    const float* wv = (const float*)d_in[8];
    const float* bv = (const float*)d_in[9];
    const float* wo = (const float*)d_in[10];
    const float* bo = (const float*)d_in[11];
    const float* gamma = (const float*)d_in[12];
    const float* beta  = (const float*)d_in[13];

    float* out  = (float*)d_out;                                   // 8M fp32 (raw out-proj, then LN in-place)
    float* attn = out + (size_t)BATCH * SEQ * DMODEL;              // 128M fp32

    char* ws = (char*)d_ws;
    uint16_t* qh   = (uint16_t*)(ws);                              // 16 MB
    uint16_t* kh   = (uint16_t*)(ws + ((size_t)16 << 20));         // 16 MB
    uint16_t* vT   = (uint16_t*)(ws + ((size_t)32 << 20));         // 16 MB
    uint16_t* ctx  = (uint16_t*)(ws + ((size_t)48 << 20));         // 16 MB
    uint16_t* wqT  = (uint16_t*)(ws + ((size_t)64 << 20));         // 2 MB each
    uint16_t* wkT  = (uint16_t*)(ws + ((size_t)66 << 20));
    uint16_t* wvT  = (uint16_t*)(ws + ((size_t)68 << 20));
    uint16_t* woT  = (uint16_t*)(ws + ((size_t)70 << 20));
    uint16_t* vtmp = (uint16_t*)(ws + ((size_t)72 << 20));         // 16 MB -> total 88 MB

    dim3 tb(256);
    wtrans_kernel<<<dim3(16, 16), tb, 0, stream>>>(wq, wqT);
    wtrans_kernel<<<dim3(16, 16), tb, 0, stream>>>(wk, wkT);
    wtrans_kernel<<<dim3(16, 16), tb, 0, stream>>>(wv, wvT);
    wtrans_kernel<<<dim3(16, 16), tb, 0, stream>>>(wo, woT);

    gemm128<true, true, false><<<dim3(8, 64), tb, 0, stream>>>(q, wqT, bq, nullptr, qh);
    gemm128<true, true, false><<<dim3(8, 64), tb, 0, stream>>>(k, wkT, bk, nullptr, kh);
    gemm128<true, true, false><<<dim3(8, 64), tb, 0, stream>>>(v, wvT, bv, nullptr, vtmp);

    vtrans_kernel<<<dim3(16, 16, 8), tb, 0, stream>>>(vtmp, vT);

    attn_kernel<<<dim3(64, NHEAD, BATCH), tb, 0, stream>>>(qh, kh, vT, mask, attn, ctx);

    gemm128<false, false, true><<<dim3(8, 64), tb, 0, stream>>>(ctx, woT, bo, q, out);

    ln_kernel<<<BATCH * SEQ, tb, 0, stream>>>(out, gamma, beta, out);
}

// Round 4
// 484.170 us; speedup vs baseline: 1.4444x; 1.1824x over previous
//
#include <hip/hip_runtime.h>
#include <stdint.h>

static constexpr int BATCH  = 8;
static constexpr int SEQ    = 1024;
static constexpr int DMODEL = 1024;
static constexpr int NHEAD  = 16;

typedef __attribute__((ext_vector_type(8))) short sh8;
typedef __attribute__((ext_vector_type(4))) float fl4;

__device__ __forceinline__ uint16_t f2bf(float f) {
    union { float f; uint32_t u; } a; a.f = f;
    uint32_t r = a.u + 0x7FFFu + ((a.u >> 16) & 1u);
    return (uint16_t)(r >> 16);
}

__device__ __forceinline__ float b2f(uint16_t u) {
    union { uint32_t u; float f; } a; a.u = ((uint32_t)u) << 16; return a.f;
}

__device__ __forceinline__ sh8 pack_bf8(fl4 x0, fl4 x1) {
    union { uint16_t u[8]; sh8 v; } pk;
    pk.u[0] = f2bf(x0[0]); pk.u[1] = f2bf(x0[1]); pk.u[2] = f2bf(x0[2]); pk.u[3] = f2bf(x0[3]);
    pk.u[4] = f2bf(x1[0]); pk.u[5] = f2bf(x1[1]); pk.u[6] = f2bf(x1[2]); pk.u[7] = f2bf(x1[3]);
    return pk.v;
}

__device__ __forceinline__ fl4 mfma16(sh8 a, sh8 b, fl4 c) {
    return __builtin_amdgcn_mfma_f32_16x16x32_bf16(a, b, c, 0, 0, 0);
}

// async global->LDS, 16B per lane; lds dest = wave-uniform base + lane*16
__device__ __forceinline__ void gload16(const void* g, void* l) {
    __builtin_amdgcn_global_load_lds(
        (const __attribute__((address_space(1))) void*)g,
        (__attribute__((address_space(3))) void*)l, 16, 0, 0);
}

// ---------------- fp32 -> bf16 bulk convert (8M elements)
__global__ __launch_bounds__(256) void cvt_bf16_kernel(const float* __restrict__ src,
                                                       uint16_t* __restrict__ dst) {
    const int t = blockIdx.x * 256 + threadIdx.x;
    #pragma unroll
    for (int it = 0; it < 2; ++it) {
        const int i = (it * 524288 + t) * 8;
        fl4 x0 = *(const fl4*)(src + i), x1 = *(const fl4*)(src + i + 4);
        *(sh8*)(dst + i) = pack_bf8(x0, x1);
    }
}

// ---------------- weight transpose + fp32->bf16 convert: wT[n][k] = w[k][n]
__global__ __launch_bounds__(256) void wtrans_kernel(const float* __restrict__ w,
                                                     uint16_t* __restrict__ wT) {
    __shared__ uint16_t T[64][72];
    const int n0 = blockIdx.x * 64, k0 = blockIdx.y * 64;
    const int tid = threadIdx.x;
    #pragma unroll
    for (int it = 0; it < 4; ++it) {
        int g = it * 256 + tid;
        int r = g >> 4, c = (g & 15) * 4;
        fl4 x = *(const fl4*)(w + (size_t)(k0 + r) * DMODEL + n0 + c);
        T[r][c + 0] = f2bf(x[0]); T[r][c + 1] = f2bf(x[1]);
        T[r][c + 2] = f2bf(x[2]); T[r][c + 3] = f2bf(x[3]);
    }
    __syncthreads();
    #pragma unroll
    for (int it = 0; it < 4; ++it) {
        int g = it * 256 + tid;
        int r = g >> 4, c = (g & 15) * 4;
        ushort4 o;
        o.x = T[c + 0][r]; o.y = T[c + 1][r]; o.z = T[c + 2][r]; o.w = T[c + 3][r];
        *(ushort4*)(wT + (size_t)(n0 + r) * DMODEL + k0 + c) = o;
    }
}

// ---------------- per-batch 1024x1024 bf16 transpose: vT[b*1024+hd][l] = vh[b*1024+l][hd]
__global__ __launch_bounds__(256) void vtrans_kernel(const uint16_t* __restrict__ vh,
                                                     uint16_t* __restrict__ vT) {
    __shared__ uint16_t T[64][72];
    const int l0 = blockIdx.x * 64, hd0 = blockIdx.y * 64, bb = blockIdx.z;
    const uint16_t* src = vh + (size_t)bb * SEQ * DMODEL;
    uint16_t* dst = vT + (size_t)bb * SEQ * DMODEL;
    const int tid = threadIdx.x;
    #pragma unroll
    for (int it = 0; it < 4; ++it) {
        int g = it * 256 + tid;
        int r = g >> 4, c = (g & 15) * 4;
        ushort4 x = *(const ushort4*)(src + (size_t)(l0 + r) * DMODEL + hd0 + c);
        T[r][c + 0] = x.x; T[r][c + 1] = x.y; T[r][c + 2] = x.z; T[r][c + 3] = x.w;
    }
    __syncthreads();
    #pragma unroll
    for (int it = 0; it < 4; ++it) {
        int g = it * 256 + tid;
        int r = g >> 4, c = (g & 15) * 4;
        ushort4 o;
        o.x = T[c + 0][r]; o.y = T[c + 1][r]; o.z = T[c + 2][r]; o.w = T[c + 3][r];
        *(ushort4*)(dst + (size_t)(hd0 + r) * DMODEL + l0 + c) = o;
    }
}

// ---------------- GEMM (bf16 A): C[8192,1024] = A * Bt^T + bias (+resid); global_load_lds staging
template<bool OUT_BF16, bool RESID>
__global__ __launch_bounds__(256)
void gemm128(const uint16_t* __restrict__ Ab, const uint16_t* __restrict__ Bt,
             const float* __restrict__ bias, const float* __restrict__ resid,
             void* __restrict__ Cv) {
    __shared__ uint16_t Alds[128 * 64];
    __shared__ uint16_t Blds[128 * 64];
    const int tid = threadIdx.x;
    const int m0 = blockIdx.y * 128, n0 = blockIdx.x * 128;
    const int lane = tid & 63, wid = tid >> 6;
    const int wr = (wid >> 1) * 64, wc = (wid & 1) * 64;
    const int fr = lane & 15, fk = (lane >> 4) * 8;

    fl4 acc[4][4];
    #pragma unroll
    for (int i = 0; i < 4; ++i)
        #pragma unroll
        for (int j = 0; j < 4; ++j) acc[i][j] = (fl4){0.f, 0.f, 0.f, 0.f};

    for (int kt = 0; kt < 16; ++kt) {
        const int kb = kt * 64;
        #pragma unroll
        for (int it = 0; it < 4; ++it) {
            const int g = it * 256 + tid;
            const int r = g >> 3, c = (g & 7) << 3;
            const int lofs = __builtin_amdgcn_readfirstlane((it * 256 + wid * 64) * 16);
            gload16(Ab + (size_t)(m0 + r) * DMODEL + kb + c, (char*)Alds + lofs);
            gload16(Bt + (size_t)(n0 + r) * DMODEL + kb + c, (char*)Blds + lofs);
        }
        __syncthreads();
        #pragma unroll
        for (int ks = 0; ks < 2; ++ks) {
            sh8 a[4], bb[4];
            #pragma unroll
            for (int mi = 0; mi < 4; ++mi) a[mi] = *(const sh8*)&Alds[(wr + mi * 16 + fr) * 64 + ks * 32 + fk];
            #pragma unroll
            for (int ni = 0; ni < 4; ++ni) bb[ni] = *(const sh8*)&Blds[(wc + ni * 16 + fr) * 64 + ks * 32 + fk];
            #pragma unroll
            for (int mi = 0; mi < 4; ++mi)
                #pragma unroll
                for (int ni = 0; ni < 4; ++ni) acc[mi][ni] = mfma16(a[mi], bb[ni], acc[mi][ni]);
        }
        __syncthreads();
    }

    #pragma unroll
    for (int mi = 0; mi < 4; ++mi) {
        #pragma unroll
        for (int ni = 0; ni < 4; ++ni) {
            const int col = n0 + wc + ni * 16 + fr;
            const float bv = bias[col];
            #pragma unroll
            for (int i = 0; i < 4; ++i) {
                const int row = m0 + wr + mi * 16 + (lane >> 4) * 4 + i;
                float val = acc[mi][ni][i] + bv;
                if (RESID) val += resid[(size_t)row * DMODEL + col];
                if (OUT_BF16) ((uint16_t*)Cv)[(size_t)row * DMODEL + col] = f2bf(val);
                else          ((float*)Cv)[(size_t)row * DMODEL + col] = val;
            }
        }
    }
}

// ---------------- attention: one block = (b, h, 16 q-rows); S bf16[16][1024] (32KB), XOR-swizzled
// unnormalized exp kept in S; normalization deferred (attn write x rinv, ctx x rinv)
__global__ __launch_bounds__(256)
void attn_kernel(const uint16_t* __restrict__ qh, const uint16_t* __restrict__ kh,
                 const uint16_t* __restrict__ vT, const uint8_t* __restrict__ mask,
                 float* __restrict__ attn, uint16_t* __restrict__ ctx) {
    __shared__ uint16_t S[16 * 1024];       // 32 KB
    __shared__ float rinv[16];
    const int q0 = blockIdx.x * 16, h = blockIdx.y, b = blockIdx.z;
    const int tid = threadIdx.x, lane = tid & 63, wid = tid >> 6;
    const int fr = lane & 15, fk = (lane >> 4) * 8, frow4 = (lane >> 4) * 4;

    // Q fragments (16x64 tile, each wave holds full copy)
    sh8 Aq[2];
    #pragma unroll
    for (int ks = 0; ks < 2; ++ks)
        Aq[ks] = *(const sh8*)(qh + (size_t)(b * SEQ + q0 + fr) * DMODEL + h * 64 + ks * 32 + fk);

    // phase 1: S = bf16(QK^T * 0.125); wave wid covers kv tiles {wid, wid+4, ...}
    for (int t8 = 0; t8 < 8; ++t8) {
        const int kv0 = (t8 * 4 + wid) * 32;
        sh8 Bk[2][2];
        #pragma unroll
        for (int ni = 0; ni < 2; ++ni)
            #pragma unroll
            for (int ks = 0; ks < 2; ++ks)
                Bk[ni][ks] = *(const sh8*)(kh + (size_t)(b * SEQ + kv0 + ni * 16 + fr) * DMODEL + h * 64 + ks * 32 + fk);
        fl4 sa[2];
        #pragma unroll
        for (int ni = 0; ni < 2; ++ni) sa[ni] = (fl4){0.f, 0.f, 0.f, 0.f};
        #pragma unroll
        for (int ni = 0; ni < 2; ++ni)
            #pragma unroll
            for (int ks = 0; ks < 2; ++ks) sa[ni] = mfma16(Aq[ks], Bk[ni][ks], sa[ni]);
        #pragma unroll
        for (int ni = 0; ni < 2; ++ni)
            #pragma unroll
            for (int i = 0; i < 4; ++i) {
                const int row = frow4 + i, col = kv0 + ni * 16 + fr;
                S[row * 1024 + ((((col >> 3) ^ (row & 15)) << 3) | (col & 7))] = f2bf(sa[ni][i] * 0.125f);
            }
    }
    __syncthreads();

    // phase 2: masked softmax stats; 16 lanes/row, interleaved 16B chunks (8 per lane)
    {
        const int r = tid >> 4, j = tid & 15;
        const int rbase = r * 1024;
        const int rx = r & 15;
        const uint8_t* mbase = mask + (size_t)(b * SEQ + q0 + r) * SEQ;
        // pass A: load + mask -> masked bf16 writeback, track max
        float mx = -1e30f;
        #pragma unroll
        for (int c4 = 0; c4 < 8; ++c4) {
            const int cc = c4 * 16 + j;
            const int so = rbase + ((cc ^ rx) << 3);
            sh8 sv = *(sh8*)&S[so];
            const uint2 mw = *(const uint2*)(mbase + cc * 8);
            union { uint16_t u[8]; sh8 v; } o;
            #pragma unroll
            for (int t = 0; t < 4; ++t) {
                float f = b2f((uint16_t)sv[t]);
                if ((mw.x >> (t * 8)) & 0xFF) f = -1e9f;
                o.u[t] = f2bf(f);
                mx = fmaxf(mx, f);
            }
            #pragma unroll
            for (int t = 0; t < 4; ++t) {
                float f = b2f((uint16_t)sv[4 + t]);
                if ((mw.y >> (t * 8)) & 0xFF) f = -1e9f;
                o.u[4 + t] = f2bf(f);
                mx = fmaxf(mx, f);
            }
            *(sh8*)&S[so] = o.v;
        }
        #pragma unroll
        for (int d = 1; d < 16; d <<= 1) mx = fmaxf(mx, __shfl_xor(mx, d));
        // pass B: exp(s - mx) -> bf16 writeback, track sum
        float sum = 0.f;
        #pragma unroll
        for (int c4 = 0; c4 < 8; ++c4) {
            const int cc = c4 * 16 + j;
            const int so = rbase + ((cc ^ rx) << 3);
            sh8 sv = *(sh8*)&S[so];
            union { uint16_t u[8]; sh8 v; } o;
            #pragma unroll
            for (int t = 0; t < 8; ++t) {
                float e = __expf(b2f((uint16_t)sv[t]) - mx);
                o.u[t] = f2bf(e);
                sum += e;
            }
            *(sh8*)&S[so] = o.v;
        }
        #pragma unroll
        for (int d = 1; d < 16; d <<= 1) sum += __shfl_xor(sum, d);
        if (j == 0) rinv[r] = 1.f / sum;
    }
    __syncthreads();

    // phase 2c: attn global write = S * rinv, fp32, nontemporal (pure streaming)
    {
        float* ab = attn + ((size_t)((h * BATCH + b) * SEQ + q0)) * SEQ;
        #pragma unroll
        for (int it = 0; it < 8; ++it) {
            const int gch = it * 256 + tid;         // 16B chunk id over 16 rows x 128 chunks
            const int row = gch >> 7, cc = gch & 127;
            sh8 p = *(sh8*)&S[row * 1024 + ((cc ^ (row & 15)) << 3)];
            const float ri = rinv[row];
            fl4 o0, o1;
            #pragma unroll
            for (int t = 0; t < 4; ++t) o0[t] = b2f((uint16_t)p[t]) * ri;
            #pragma unroll
            for (int t = 0; t < 4; ++t) o1[t] = b2f((uint16_t)p[4 + t]) * ri;
            float* dst = ab + (size_t)gch * 8;
            __builtin_nontemporal_store(o0, (fl4*)dst);
            __builtin_nontemporal_store(o1, (fl4*)(dst + 4));
        }
    }

    // phase 3: ctx = (P_unnorm V) * rinv ; wave wid owns d-block [wid*16, wid*16+16)
    fl4 acc0 = (fl4){0.f, 0.f, 0.f, 0.f}, acc1 = (fl4){0.f, 0.f, 0.f, 0.f};
    const uint16_t* vbase = vT + (size_t)((b * NHEAD + h) * 64 + wid * 16) * SEQ;
    const int frx = fr & 15;
    #pragma unroll 4
    for (int ks2 = 0; ks2 < 32; ++ks2) {
        const int kv = ks2 * 32;
        sh8 Ap = *(const sh8*)&S[fr * 1024 + ((((kv + fk) >> 3) ^ frx) << 3)];
        sh8 Bv = *(const sh8*)(vbase + (size_t)fr * SEQ + kv + fk);
        if (ks2 & 1) acc1 = mfma16(Ap, Bv, acc1);
        else         acc0 = mfma16(Ap, Bv, acc0);
    }
    #pragma unroll
    for (int i = 0; i < 4; ++i) {
        const int q = frow4 + i;
        const float val = (acc0[i] + acc1[i]) * rinv[q];
        ctx[(size_t)(b * SEQ + q0 + q) * DMODEL + h * 64 + wid * 16 + fr] = f2bf(val);
    }
}

// ---------------- LayerNorm (in-place capable): one block per row
__global__ __launch_bounds__(256)
void ln_kernel(const float* __restrict__ raw, const float* __restrict__ gamma,
               const float* __restrict__ beta, float* __restrict__ out) {
    const int row = blockIdx.x;
    const int tid = threadIdx.x;
    const float* x = raw + (size_t)row * DMODEL;
    fl4 xv = *(const fl4*)(x + tid * 4);
    float s  = xv[0] + xv[1] + xv[2] + xv[3];
    float ss = xv[0] * xv[0] + xv[1] * xv[1] + xv[2] * xv[2] + xv[3] * xv[3];
    #pragma unroll
    for (int d = 1; d < 64; d <<= 1) { s += __shfl_xor(s, d); ss += __shfl_xor(ss, d); }
    __shared__ float sb[4], ssb[4];
    if ((tid & 63) == 0) { sb[tid >> 6] = s; ssb[tid >> 6] = ss; }
    __syncthreads();
    s  = sb[0] + sb[1] + sb[2] + sb[3];
    ss = ssb[0] + ssb[1] + ssb[2] + ssb[3];
    const float mu  = s * (1.f / 1024.f);
    const float var = ss * (1.f / 1024.f) - mu * mu;
    const float rstd = rsqrtf(var + 1e-5f);
    fl4 g  = *(const fl4*)(gamma + tid * 4);
    fl4 be = *(const fl4*)(beta + tid * 4);
    fl4 o;
    #pragma unroll
    for (int j = 0; j < 4; ++j) o[j] = (xv[j] - mu) * rstd * g[j] + be[j];
    *(fl4*)(out + (size_t)row * DMODEL + tid * 4) = o;
}

extern "C" void kernel_launch(void* const* d_in, const int* in_sizes, int n_in,
                              void* d_out, int out_size, void* d_ws, size_t ws_size,
                              hipStream_t stream) {
    (void)in_sizes; (void)n_in; (void)out_size; (void)ws_size;
    const float* q     = (const float*)d_in[0];
    const float* k     = (const float*)d_in[1];
    const float* v     = (const float*)d_in[2];
    const uint8_t* mask = (const uint8_t*)d_in[3];
    const float* wq = (const float*)d_in[4];
    const float* bq = (const float*)d_in[5];
    const float* wk = (const float*)d_in[6];
    const float* bk = (const float*)d_in[7];
    const float* wv = (const float*)d_in[8];
    const float* bv = (const float*)d_in[9];
    const float* wo = (const float*)d_in[10];
    const float* bo = (const float*)d_in[11];
    const float* gamma = (const float*)d_in[12];
    const float* beta  = (const float*)d_in[13];

    float* out  = (float*)d_out;                                   // 8M fp32 (raw out-proj, then LN in-place)
    float* attn = out + (size_t)BATCH * SEQ * DMODEL;              // 128M fp32

    // bf16 copies of q/k/v live in the attn output region (written only later by attn_kernel)
    uint16_t* qcvt = (uint16_t*)(attn);
    uint16_t* kcvt = (uint16_t*)((char*)attn + ((size_t)16 << 20));
    uint16_t* vcvt = (uint16_t*)((char*)attn + ((size_t)32 << 20));

    char* ws = (char*)d_ws;
    uint16_t* qh   = (uint16_t*)(ws);                              // 16 MB
    uint16_t* kh   = (uint16_t*)(ws + ((size_t)16 << 20));         // 16 MB
    uint16_t* vT   = (uint16_t*)(ws + ((size_t)32 << 20));         // 16 MB
    uint16_t* ctx  = (uint16_t*)(ws + ((size_t)48 << 20));         // 16 MB
    uint16_t* wqT  = (uint16_t*)(ws + ((size_t)64 << 20));         // 2 MB each
    uint16_t* wkT  = (uint16_t*)(ws + ((size_t)66 << 20));
    uint16_t* wvT  = (uint16_t*)(ws + ((size_t)68 << 20));
    uint16_t* woT  = (uint16_t*)(ws + ((size_t)70 << 20));
    uint16_t* vtmp = (uint16_t*)(ws + ((size_t)72 << 20));         // 16 MB -> total 88 MB

    dim3 tb(256);
    wtrans_kernel<<<dim3(16, 16), tb, 0, stream>>>(wq, wqT);
    wtrans_kernel<<<dim3(16, 16), tb, 0, stream>>>(wk, wkT);
    wtrans_kernel<<<dim3(16, 16), tb, 0, stream>>>(wv, wvT);
    wtrans_kernel<<<dim3(16, 16), tb, 0, stream>>>(wo, woT);

    cvt_bf16_kernel<<<2048, tb, 0, stream>>>(q, qcvt);
    cvt_bf16_kernel<<<2048, tb, 0, stream>>>(k, kcvt);
    cvt_bf16_kernel<<<2048, tb, 0, stream>>>(v, vcvt);

    gemm128<true, false><<<dim3(8, 64), tb, 0, stream>>>(qcvt, wqT, bq, nullptr, qh);
    gemm128<true, false><<<dim3(8, 64), tb, 0, stream>>>(kcvt, wkT, bk, nullptr, kh);
    gemm128<true, false><<<dim3(8, 64), tb, 0, stream>>>(vcvt, wvT, bv, nullptr, vtmp);

    vtrans_kernel<<<dim3(16, 16, 8), tb, 0, stream>>>(vtmp, vT);

    attn_kernel<<<dim3(64, NHEAD, BATCH), tb, 0, stream>>>(qh, kh, vT, mask, attn, ctx);

    gemm128<false, true><<<dim3(8, 64), tb, 0, stream>>>(ctx, woT, bo, q, out);

    ln_kernel<<<BATCH * SEQ, tb, 0, stream>>>(out, gamma, beta, out);
}

// Round 5
// 456.440 us; speedup vs baseline: 1.5322x; 1.0608x over previous
//
#include <hip/hip_runtime.h>
#include <stdint.h>

static constexpr int BATCH  = 8;
static constexpr int SEQ    = 1024;
static constexpr int DMODEL = 1024;
static constexpr int NHEAD  = 16;

typedef __attribute__((ext_vector_type(8))) short sh8;
typedef __attribute__((ext_vector_type(4))) float fl4;

__device__ __forceinline__ uint16_t f2bf(float f) {
    union { float f; uint32_t u; } a; a.f = f;
    uint32_t r = a.u + 0x7FFFu + ((a.u >> 16) & 1u);
    return (uint16_t)(r >> 16);
}

__device__ __forceinline__ float b2f(uint16_t u) {
    union { uint32_t u; float f; } a; a.u = ((uint32_t)u) << 16; return a.f;
}

__device__ __forceinline__ sh8 pack_bf8(fl4 x0, fl4 x1) {
    union { uint16_t u[8]; sh8 v; } pk;
    pk.u[0] = f2bf(x0[0]); pk.u[1] = f2bf(x0[1]); pk.u[2] = f2bf(x0[2]); pk.u[3] = f2bf(x0[3]);
    pk.u[4] = f2bf(x1[0]); pk.u[5] = f2bf(x1[1]); pk.u[6] = f2bf(x1[2]); pk.u[7] = f2bf(x1[3]);
    return pk.v;
}

__device__ __forceinline__ fl4 mfma16(sh8 a, sh8 b, fl4 c) {
    return __builtin_amdgcn_mfma_f32_16x16x32_bf16(a, b, c, 0, 0, 0);
}

// async global->LDS, 16B per lane; lds dest = wave-uniform base + lane*16
__device__ __forceinline__ void gload16(const void* g, void* l) {
    __builtin_amdgcn_global_load_lds(
        (const __attribute__((address_space(1))) void*)g,
        (__attribute__((address_space(3))) void*)l, 16, 0, 0);
}

// ---------------- fused fp32 -> bf16 bulk convert for q,k,v (z selects tensor)
__global__ __launch_bounds__(256) void cvt3_kernel(const float* __restrict__ q,
                                                   const float* __restrict__ k,
                                                   const float* __restrict__ v,
                                                   uint16_t* __restrict__ dq,
                                                   uint16_t* __restrict__ dk,
                                                   uint16_t* __restrict__ dv) {
    const int z = blockIdx.z;
    const float* src = (z == 0) ? q : (z == 1) ? k : v;
    uint16_t* dst = (z == 0) ? dq : (z == 1) ? dk : dv;
    const int t = blockIdx.x * 256 + threadIdx.x;
    #pragma unroll
    for (int it = 0; it < 2; ++it) {
        const int i = (it * 524288 + t) * 8;
        fl4 x0 = *(const fl4*)(src + i), x1 = *(const fl4*)(src + i + 4);
        *(sh8*)(dst + i) = pack_bf8(x0, x1);
    }
}

// ---------------- fused weight transpose + fp32->bf16: wT[n][k] = w[k][n]; z selects weight
__global__ __launch_bounds__(256) void wtrans_kernel(const float* __restrict__ wq, const float* __restrict__ wk,
                                                     const float* __restrict__ wv, const float* __restrict__ wo,
                                                     uint16_t* __restrict__ tq, uint16_t* __restrict__ tk,
                                                     uint16_t* __restrict__ tv, uint16_t* __restrict__ to) {
    __shared__ uint16_t T[64][72];
    const int z = blockIdx.z;
    const float* w = (z == 0) ? wq : (z == 1) ? wk : (z == 2) ? wv : wo;
    uint16_t* wT = (z == 0) ? tq : (z == 1) ? tk : (z == 2) ? tv : to;
    const int n0 = blockIdx.x * 64, k0 = blockIdx.y * 64;
    const int tid = threadIdx.x;
    #pragma unroll
    for (int it = 0; it < 4; ++it) {
        int g = it * 256 + tid;
        int r = g >> 4, c = (g & 15) * 4;
        fl4 x = *(const fl4*)(w + (size_t)(k0 + r) * DMODEL + n0 + c);
        T[r][c + 0] = f2bf(x[0]); T[r][c + 1] = f2bf(x[1]);
        T[r][c + 2] = f2bf(x[2]); T[r][c + 3] = f2bf(x[3]);
    }
    __syncthreads();
    #pragma unroll
    for (int it = 0; it < 4; ++it) {
        int g = it * 256 + tid;
        int r = g >> 4, c = (g & 15) * 4;
        ushort4 o;
        o.x = T[c + 0][r]; o.y = T[c + 1][r]; o.z = T[c + 2][r]; o.w = T[c + 3][r];
        *(ushort4*)(wT + (size_t)(n0 + r) * DMODEL + k0 + c) = o;
    }
}

// ---------------- per-batch 1024x1024 bf16 transpose: vT[b*1024+hd][l] = vh[b*1024+l][hd]
__global__ __launch_bounds__(256) void vtrans_kernel(const uint16_t* __restrict__ vh,
                                                     uint16_t* __restrict__ vT) {
    __shared__ uint16_t T[64][72];
    const int l0 = blockIdx.x * 64, hd0 = blockIdx.y * 64, bb = blockIdx.z;
    const uint16_t* src = vh + (size_t)bb * SEQ * DMODEL;
    uint16_t* dst = vT + (size_t)bb * SEQ * DMODEL;
    const int tid = threadIdx.x;
    #pragma unroll
    for (int it = 0; it < 4; ++it) {
        int g = it * 256 + tid;
        int r = g >> 4, c = (g & 15) * 4;
        ushort4 x = *(const ushort4*)(src + (size_t)(l0 + r) * DMODEL + hd0 + c);
        T[r][c + 0] = x.x; T[r][c + 1] = x.y; T[r][c + 2] = x.z; T[r][c + 3] = x.w;
    }
    __syncthreads();
    #pragma unroll
    for (int it = 0; it < 4; ++it) {
        int g = it * 256 + tid;
        int r = g >> 4, c = (g & 15) * 4;
        ushort4 o;
        o.x = T[c + 0][r]; o.y = T[c + 1][r]; o.z = T[c + 2][r]; o.w = T[c + 3][r];
        *(ushort4*)(dst + (size_t)(hd0 + r) * DMODEL + l0 + c) = o;
    }
}

// ---------------- GEMM core body (128x128 tile, BK=64, global_load_lds staging)
template<bool OUT_BF16, bool RESID>
__device__ __forceinline__
void gemm_body(const uint16_t* __restrict__ Ab, const uint16_t* __restrict__ Bt,
               const float* __restrict__ bias, const float* __restrict__ resid,
               void* __restrict__ Cv, int m0, int n0,
               uint16_t* Alds, uint16_t* Blds) {
    const int tid = threadIdx.x;
    const int lane = tid & 63, wid = tid >> 6;
    const int wr = (wid >> 1) * 64, wc = (wid & 1) * 64;
    const int fr = lane & 15, fk = (lane >> 4) * 8;

    fl4 acc[4][4];
    #pragma unroll
    for (int i = 0; i < 4; ++i)
        #pragma unroll
        for (int j = 0; j < 4; ++j) acc[i][j] = (fl4){0.f, 0.f, 0.f, 0.f};

    for (int kt = 0; kt < 16; ++kt) {
        const int kb = kt * 64;
        #pragma unroll
        for (int it = 0; it < 4; ++it) {
            const int g = it * 256 + tid;
            const int r = g >> 3, c = (g & 7) << 3;
            const int lofs = __builtin_amdgcn_readfirstlane((it * 256 + wid * 64) * 16);
            gload16(Ab + (size_t)(m0 + r) * DMODEL + kb + c, (char*)Alds + lofs);
            gload16(Bt + (size_t)(n0 + r) * DMODEL + kb + c, (char*)Blds + lofs);
        }
        __syncthreads();
        #pragma unroll
        for (int ks = 0; ks < 2; ++ks) {
            sh8 a[4], bb[4];
            #pragma unroll
            for (int mi = 0; mi < 4; ++mi) a[mi] = *(const sh8*)&Alds[(wr + mi * 16 + fr) * 64 + ks * 32 + fk];
            #pragma unroll
            for (int ni = 0; ni < 4; ++ni) bb[ni] = *(const sh8*)&Blds[(wc + ni * 16 + fr) * 64 + ks * 32 + fk];
            #pragma unroll
            for (int mi = 0; mi < 4; ++mi)
                #pragma unroll
                for (int ni = 0; ni < 4; ++ni) acc[mi][ni] = mfma16(a[mi], bb[ni], acc[mi][ni]);
        }
        __syncthreads();
    }

    #pragma unroll
    for (int mi = 0; mi < 4; ++mi) {
        #pragma unroll
        for (int ni = 0; ni < 4; ++ni) {
            const int col = n0 + wc + ni * 16 + fr;
            const float bv = bias[col];
            #pragma unroll
            for (int i = 0; i < 4; ++i) {
                const int row = m0 + wr + mi * 16 + (lane >> 4) * 4 + i;
                float val = acc[mi][ni][i] + bv;
                if (RESID) val += resid[(size_t)row * DMODEL + col];
                if (OUT_BF16) ((uint16_t*)Cv)[(size_t)row * DMODEL + col] = f2bf(val);
                else          ((float*)Cv)[(size_t)row * DMODEL + col] = val;
            }
        }
    }
}

// fused projection GEMM: z selects (A, B, bias, C)
__global__ __launch_bounds__(256)
void gemm_proj(const uint16_t* __restrict__ A0, const uint16_t* __restrict__ A1, const uint16_t* __restrict__ A2,
               const uint16_t* __restrict__ B0, const uint16_t* __restrict__ B1, const uint16_t* __restrict__ B2,
               const float* __restrict__ b0, const float* __restrict__ b1, const float* __restrict__ b2,
               uint16_t* __restrict__ C0, uint16_t* __restrict__ C1, uint16_t* __restrict__ C2) {
    __shared__ uint16_t Alds[128 * 64];
    __shared__ uint16_t Blds[128 * 64];
    const int z = blockIdx.z;
    const uint16_t* Ab = (z == 0) ? A0 : (z == 1) ? A1 : A2;
    const uint16_t* Bt = (z == 0) ? B0 : (z == 1) ? B1 : B2;
    const float* bias  = (z == 0) ? b0 : (z == 1) ? b1 : b2;
    uint16_t* Cv       = (z == 0) ? C0 : (z == 1) ? C1 : C2;
    gemm_body<true, false>(Ab, Bt, bias, nullptr, Cv, blockIdx.y * 128, blockIdx.x * 128, Alds, Blds);
}

// out-proj GEMM: fp32 out + residual
__global__ __launch_bounds__(256)
void gemm_out(const uint16_t* __restrict__ Ab, const uint16_t* __restrict__ Bt,
              const float* __restrict__ bias, const float* __restrict__ resid,
              float* __restrict__ Cv) {
    __shared__ uint16_t Alds[128 * 64];
    __shared__ uint16_t Blds[128 * 64];
    gemm_body<false, true>(Ab, Bt, bias, resid, Cv, blockIdx.y * 128, blockIdx.x * 128, Alds, Blds);
}

// ---------------- attention: one block = (b, h, 16 q-rows); S bf16[16][1024] (32KB), XOR-swizzled
// softmax is register-resident; S holds unnormalized exp (bf16) for PV; attn written from regs
__global__ __launch_bounds__(256)
void attn_kernel(const uint16_t* __restrict__ qh, const uint16_t* __restrict__ kh,
                 const uint16_t* __restrict__ vT, const uint8_t* __restrict__ mask,
                 float* __restrict__ attn, uint16_t* __restrict__ ctx) {
    __shared__ uint16_t S[16 * 1024];       // 32 KB
    __shared__ float rinv[16];
    const int q0 = blockIdx.x * 16, h = blockIdx.y, b = blockIdx.z;
    const int tid = threadIdx.x, lane = tid & 63, wid = tid >> 6;
    const int fr = lane & 15, fk = (lane >> 4) * 8, frow4 = (lane >> 4) * 4;

    // Q fragments (16x64 tile, each wave holds full copy)
    sh8 Aq[2];
    #pragma unroll
    for (int ks = 0; ks < 2; ++ks)
        Aq[ks] = *(const sh8*)(qh + (size_t)(b * SEQ + q0 + fr) * DMODEL + h * 64 + ks * 32 + fk);

    // phase 1: S = bf16(QK^T * 0.125); wave wid covers kv tiles {wid, wid+4, ...}
    for (int t8 = 0; t8 < 8; ++t8) {
        const int kv0 = (t8 * 4 + wid) * 32;
        sh8 Bk[2][2];
        #pragma unroll
        for (int ni = 0; ni < 2; ++ni)
            #pragma unroll
            for (int ks = 0; ks < 2; ++ks)
                Bk[ni][ks] = *(const sh8*)(kh + (size_t)(b * SEQ + kv0 + ni * 16 + fr) * DMODEL + h * 64 + ks * 32 + fk);
        fl4 sa[2];
        #pragma unroll
        for (int ni = 0; ni < 2; ++ni) sa[ni] = (fl4){0.f, 0.f, 0.f, 0.f};
        #pragma unroll
        for (int ni = 0; ni < 2; ++ni)
            #pragma unroll
            for (int ks = 0; ks < 2; ++ks) sa[ni] = mfma16(Aq[ks], Bk[ni][ks], sa[ni]);
        #pragma unroll
        for (int ni = 0; ni < 2; ++ni)
            #pragma unroll
            for (int i = 0; i < 4; ++i) {
                const int row = frow4 + i, col = kv0 + ni * 16 + fr;
                S[row * 1024 + ((((col >> 3) ^ (row & 15)) << 3) | (col & 7))] = f2bf(sa[ni][i] * 0.125f);
            }
    }
    __syncthreads();

    // phase 2: register-resident masked softmax; 16 lanes/row, 8 interleaved 16B chunks per lane
    {
        const int r = tid >> 4, j = tid & 15;
        const int rbase = r * 1024;
        const uint8_t* mbase = mask + (size_t)(b * SEQ + q0 + r) * SEQ;
        sh8 sv[8];
        // load chunks + apply mask in regs, track max
        float mx = -1e30f;
        #pragma unroll
        for (int c4 = 0; c4 < 8; ++c4) {
            const int cc = c4 * 16 + j;
            sh8 x = *(sh8*)&S[rbase + ((cc ^ r) << 3)];
            const uint2 mw = *(const uint2*)(mbase + cc * 8);
            union { uint16_t u[8]; sh8 v; } o;
            #pragma unroll
            for (int t = 0; t < 4; ++t) {
                float f = b2f((uint16_t)x[t]);
                if ((mw.x >> (t * 8)) & 0xFF) f = -1e9f;
                o.u[t] = f2bf(f);
                mx = fmaxf(mx, f);
            }
            #pragma unroll
            for (int t = 0; t < 4; ++t) {
                float f = b2f((uint16_t)x[4 + t]);
                if ((mw.y >> (t * 8)) & 0xFF) f = -1e9f;
                o.u[4 + t] = f2bf(f);
                mx = fmaxf(mx, f);
            }
            sv[c4] = o.v;
        }
        #pragma unroll
        for (int d = 1; d < 16; d <<= 1) mx = fmaxf(mx, __shfl_xor(mx, d));
        // exp in regs -> LDS (for PV), track sum
        float sum = 0.f;
        #pragma unroll
        for (int c4 = 0; c4 < 8; ++c4) {
            const int cc = c4 * 16 + j;
            union { uint16_t u[8]; sh8 v; } o;
            #pragma unroll
            for (int t = 0; t < 8; ++t) {
                float e = __expf(b2f((uint16_t)sv[c4][t]) - mx);
                o.u[t] = f2bf(e);
                sum += e;
            }
            sv[c4] = o.v;
            *(sh8*)&S[rbase + ((cc ^ r) << 3)] = o.v;
        }
        #pragma unroll
        for (int d = 1; d < 16; d <<= 1) sum += __shfl_xor(sum, d);
        const float ri = 1.f / sum;
        if (j == 0) rinv[r] = ri;
        // normalized fp32 attn write straight from regs (nontemporal streaming)
        float* ab = attn + ((size_t)((h * BATCH + b) * SEQ + q0 + r)) * SEQ;
        #pragma unroll
        for (int c4 = 0; c4 < 8; ++c4) {
            const int cc = c4 * 16 + j;
            fl4 o0, o1;
            #pragma unroll
            for (int t = 0; t < 4; ++t) o0[t] = b2f((uint16_t)sv[c4][t]) * ri;
            #pragma unroll
            for (int t = 0; t < 4; ++t) o1[t] = b2f((uint16_t)sv[c4][4 + t]) * ri;
            float* dst = ab + cc * 8;
            __builtin_nontemporal_store(o0, (fl4*)dst);
            __builtin_nontemporal_store(o1, (fl4*)(dst + 4));
        }
    }
    __syncthreads();

    // phase 3: ctx = (P_unnorm V) * rinv ; wave wid owns d-block [wid*16, wid*16+16)
    fl4 acc0 = (fl4){0.f, 0.f, 0.f, 0.f}, acc1 = (fl4){0.f, 0.f, 0.f, 0.f};
    const uint16_t* vbase = vT + (size_t)((b * NHEAD + h) * 64 + wid * 16) * SEQ;
    const int frx = fr & 15;
    #pragma unroll 4
    for (int ks2 = 0; ks2 < 32; ++ks2) {
        const int kv = ks2 * 32;
        sh8 Ap = *(const sh8*)&S[fr * 1024 + ((((kv + fk) >> 3) ^ frx) << 3)];
        sh8 Bv = *(const sh8*)(vbase + (size_t)fr * SEQ + kv + fk);
        if (ks2 & 1) acc1 = mfma16(Ap, Bv, acc1);
        else         acc0 = mfma16(Ap, Bv, acc0);
    }
    #pragma unroll
    for (int i = 0; i < 4; ++i) {
        const int q = frow4 + i;
        const float val = (acc0[i] + acc1[i]) * rinv[q];
        ctx[(size_t)(b * SEQ + q0 + q) * DMODEL + h * 64 + wid * 16 + fr] = f2bf(val);
    }
}

// ---------------- LayerNorm (in-place capable): one block per row
__global__ __launch_bounds__(256)
void ln_kernel(const float* __restrict__ raw, const float* __restrict__ gamma,
               const float* __restrict__ beta, float* __restrict__ out) {
    const int row = blockIdx.x;
    const int tid = threadIdx.x;
    const float* x = raw + (size_t)row * DMODEL;
    fl4 xv = *(const fl4*)(x + tid * 4);
    float s  = xv[0] + xv[1] + xv[2] + xv[3];
    float ss = xv[0] * xv[0] + xv[1] * xv[1] + xv[2] * xv[2] + xv[3] * xv[3];
    #pragma unroll
    for (int d = 1; d < 64; d <<= 1) { s += __shfl_xor(s, d); ss += __shfl_xor(ss, d); }
    __shared__ float sb[4], ssb[4];
    if ((tid & 63) == 0) { sb[tid >> 6] = s; ssb[tid >> 6] = ss; }
    __syncthreads();
    s  = sb[0] + sb[1] + sb[2] + sb[3];
    ss = ssb[0] + ssb[1] + ssb[2] + ssb[3];
    const float mu  = s * (1.f / 1024.f);
    const float var = ss * (1.f / 1024.f) - mu * mu;
    const float rstd = rsqrtf(var + 1e-5f);
    fl4 g  = *(const fl4*)(gamma + tid * 4);
    fl4 be = *(const fl4*)(beta + tid * 4);
    fl4 o;
    #pragma unroll
    for (int j = 0; j < 4; ++j) o[j] = (xv[j] - mu) * rstd * g[j] + be[j];
    *(fl4*)(out + (size_t)row * DMODEL + tid * 4) = o;
}

extern "C" void kernel_launch(void* const* d_in, const int* in_sizes, int n_in,
                              void* d_out, int out_size, void* d_ws, size_t ws_size,
                              hipStream_t stream) {
    (void)in_sizes; (void)n_in; (void)out_size; (void)ws_size;
    const float* q     = (const float*)d_in[0];
    const float* k     = (const float*)d_in[1];
    const float* v     = (const float*)d_in[2];
    const uint8_t* mask = (const uint8_t*)d_in[3];
    const float* wq = (const float*)d_in[4];
    const float* bq = (const float*)d_in[5];
    const float* wk = (const float*)d_in[6];
    const float* bk = (const float*)d_in[7];
    const float* wv = (const float*)d_in[8];
    const float* bv = (const float*)d_in[9];
    const float* wo = (const float*)d_in[10];
    const float* bo = (const float*)d_in[11];
    const float* gamma = (const float*)d_in[12];
    const float* beta  = (const float*)d_in[13];

    float* out  = (float*)d_out;                                   // 8M fp32 (raw out-proj, then LN in-place)
    float* attn = out + (size_t)BATCH * SEQ * DMODEL;              // 128M fp32

    // bf16 copies of q/k/v live in the attn output region (consumed before attn_kernel writes it)
    uint16_t* qcvt = (uint16_t*)(attn);
    uint16_t* kcvt = (uint16_t*)((char*)attn + ((size_t)16 << 20));
    uint16_t* vcvt = (uint16_t*)((char*)attn + ((size_t)32 << 20));

    char* ws = (char*)d_ws;
    uint16_t* qh   = (uint16_t*)(ws);                              // 16 MB
    uint16_t* kh   = (uint16_t*)(ws + ((size_t)16 << 20));         // 16 MB
    uint16_t* vT   = (uint16_t*)(ws + ((size_t)32 << 20));         // 16 MB
    uint16_t* ctx  = (uint16_t*)(ws + ((size_t)48 << 20));         // 16 MB
    uint16_t* wqT  = (uint16_t*)(ws + ((size_t)64 << 20));         // 2 MB each
    uint16_t* wkT  = (uint16_t*)(ws + ((size_t)66 << 20));
    uint16_t* wvT  = (uint16_t*)(ws + ((size_t)68 << 20));
    uint16_t* woT  = (uint16_t*)(ws + ((size_t)70 << 20));
    uint16_t* vtmp = (uint16_t*)(ws + ((size_t)72 << 20));         // 16 MB -> total 88 MB

    dim3 tb(256);
    wtrans_kernel<<<dim3(16, 16, 4), tb, 0, stream>>>(wq, wk, wv, wo, wqT, wkT, wvT, woT);
    cvt3_kernel<<<dim3(2048, 1, 3), tb, 0, stream>>>(q, k, v, qcvt, kcvt, vcvt);

    gemm_proj<<<dim3(8, 64, 3), tb, 0, stream>>>(qcvt, kcvt, vcvt, wqT, wkT, wvT,
                                                 bq, bk, bv, qh, kh, vtmp);

    vtrans_kernel<<<dim3(16, 16, 8), tb, 0, stream>>>(vtmp, vT);

    attn_kernel<<<dim3(64, NHEAD, BATCH), tb, 0, stream>>>(qh, kh, vT, mask, attn, ctx);

    gemm_out<<<dim3(8, 64), tb, 0, stream>>>(ctx, woT, bo, q, out);

    ln_kernel<<<BATCH * SEQ, tb, 0, stream>>>(out, gamma, beta, out);
}

// Round 6
// 455.238 us; speedup vs baseline: 1.5362x; 1.0026x over previous
//
#include <hip/hip_runtime.h>
#include <stdint.h>

static constexpr int BATCH  = 8;
static constexpr int SEQ    = 1024;
static constexpr int DMODEL = 1024;
static constexpr int NHEAD  = 16;

typedef __attribute__((ext_vector_type(8))) short sh8;
typedef __attribute__((ext_vector_type(4))) float fl4;

__device__ __forceinline__ uint16_t f2bf(float f) {
    union { float f; uint32_t u; } a; a.f = f;
    uint32_t r = a.u + 0x7FFFu + ((a.u >> 16) & 1u);
    return (uint16_t)(r >> 16);
}

__device__ __forceinline__ float b2f(uint16_t u) {
    union { uint32_t u; float f; } a; a.u = ((uint32_t)u) << 16; return a.f;
}

// HW packed fp32->bf16 (RNE): low16 = cvt(lo), high16 = cvt(hi)
__device__ __forceinline__ uint32_t cvtpk(float lo, float hi) {
    uint32_t r;
    asm("v_cvt_pk_bf16_f32 %0, %1, %2" : "=v"(r) : "v"(lo), "v"(hi));
    return r;
}

__device__ __forceinline__ sh8 pack_bf8(fl4 x0, fl4 x1) {
    union { uint32_t w[4]; sh8 v; } pk;
    pk.w[0] = cvtpk(x0[0], x0[1]); pk.w[1] = cvtpk(x0[2], x0[3]);
    pk.w[2] = cvtpk(x1[0], x1[1]); pk.w[3] = cvtpk(x1[2], x1[3]);
    return pk.v;
}

__device__ __forceinline__ fl4 mfma16(sh8 a, sh8 b, fl4 c) {
    return __builtin_amdgcn_mfma_f32_16x16x32_bf16(a, b, c, 0, 0, 0);
}

// async global->LDS, 16B per lane; lds dest = wave-uniform base + lane*16
__device__ __forceinline__ void gload16(const void* g, void* l) {
    __builtin_amdgcn_global_load_lds(
        (const __attribute__((address_space(1))) void*)g,
        (__attribute__((address_space(3))) void*)l, 16, 0, 0);
}

// ---------------- fused fp32 -> bf16 bulk convert for q,k,v (z selects tensor)
__global__ __launch_bounds__(256) void cvt3_kernel(const float* __restrict__ q,
                                                   const float* __restrict__ k,
                                                   const float* __restrict__ v,
                                                   uint16_t* __restrict__ dq,
                                                   uint16_t* __restrict__ dk,
                                                   uint16_t* __restrict__ dv) {
    const int z = blockIdx.z;
    const float* src = (z == 0) ? q : (z == 1) ? k : v;
    uint16_t* dst = (z == 0) ? dq : (z == 1) ? dk : dv;
    const int t = blockIdx.x * 256 + threadIdx.x;
    #pragma unroll
    for (int it = 0; it < 2; ++it) {
        const int i = (it * 524288 + t) * 8;
        fl4 x0 = *(const fl4*)(src + i), x1 = *(const fl4*)(src + i + 4);
        *(sh8*)(dst + i) = pack_bf8(x0, x1);
    }
}

// ---------------- fused weight transpose + fp32->bf16: wT[n][k] = w[k][n]; z selects weight
// z==0 (wq) is pre-scaled by 0.125 (1/sqrt(dk)) so QK^T needs no scaling
__global__ __launch_bounds__(256) void wtrans_kernel(const float* __restrict__ wq, const float* __restrict__ wk,
                                                     const float* __restrict__ wv, const float* __restrict__ wo,
                                                     uint16_t* __restrict__ tq, uint16_t* __restrict__ tk,
                                                     uint16_t* __restrict__ tv, uint16_t* __restrict__ to) {
    __shared__ uint16_t T[64][72];
    const int z = blockIdx.z;
    const float* w = (z == 0) ? wq : (z == 1) ? wk : (z == 2) ? wv : wo;
    uint16_t* wT = (z == 0) ? tq : (z == 1) ? tk : (z == 2) ? tv : to;
    const float ws = (z == 0) ? 0.125f : 1.f;
    const int n0 = blockIdx.x * 64, k0 = blockIdx.y * 64;
    const int tid = threadIdx.x;
    #pragma unroll
    for (int it = 0; it < 4; ++it) {
        int g = it * 256 + tid;
        int r = g >> 4, c = (g & 15) * 4;
        fl4 x = *(const fl4*)(w + (size_t)(k0 + r) * DMODEL + n0 + c);
        T[r][c + 0] = f2bf(x[0] * ws); T[r][c + 1] = f2bf(x[1] * ws);
        T[r][c + 2] = f2bf(x[2] * ws); T[r][c + 3] = f2bf(x[3] * ws);
    }
    __syncthreads();
    #pragma unroll
    for (int it = 0; it < 4; ++it) {
        int g = it * 256 + tid;
        int r = g >> 4, c = (g & 15) * 4;
        ushort4 o;
        o.x = T[c + 0][r]; o.y = T[c + 1][r]; o.z = T[c + 2][r]; o.w = T[c + 3][r];
        *(ushort4*)(wT + (size_t)(n0 + r) * DMODEL + k0 + c) = o;
    }
}

// ---------------- per-batch 1024x1024 bf16 transpose: vT[b*1024+hd][l] = vh[b*1024+l][hd]
__global__ __launch_bounds__(256) void vtrans_kernel(const uint16_t* __restrict__ vh,
                                                     uint16_t* __restrict__ vT) {
    __shared__ uint16_t T[64][72];
    const int l0 = blockIdx.x * 64, hd0 = blockIdx.y * 64, bb = blockIdx.z;
    const uint16_t* src = vh + (size_t)bb * SEQ * DMODEL;
    uint16_t* dst = vT + (size_t)bb * SEQ * DMODEL;
    const int tid = threadIdx.x;
    #pragma unroll
    for (int it = 0; it < 4; ++it) {
        int g = it * 256 + tid;
        int r = g >> 4, c = (g & 15) * 4;
        ushort4 x = *(const ushort4*)(src + (size_t)(l0 + r) * DMODEL + hd0 + c);
        T[r][c + 0] = x.x; T[r][c + 1] = x.y; T[r][c + 2] = x.z; T[r][c + 3] = x.w;
    }
    __syncthreads();
    #pragma unroll
    for (int it = 0; it < 4; ++it) {
        int g = it * 256 + tid;
        int r = g >> 4, c = (g & 15) * 4;
        ushort4 o;
        o.x = T[c + 0][r]; o.y = T[c + 1][r]; o.z = T[c + 2][r]; o.w = T[c + 3][r];
        *(ushort4*)(dst + (size_t)(hd0 + r) * DMODEL + l0 + c) = o;
    }
}

// ---------------- GEMM core body (128x128 tile, BK=64, global_load_lds staging)
template<bool OUT_BF16, bool RESID>
__device__ __forceinline__
void gemm_body(const uint16_t* __restrict__ Ab, const uint16_t* __restrict__ Bt,
               const float* __restrict__ bias, float bscale, const float* __restrict__ resid,
               void* __restrict__ Cv, int m0, int n0,
               uint16_t* Alds, uint16_t* Blds) {
    const int tid = threadIdx.x;
    const int lane = tid & 63, wid = tid >> 6;
    const int wr = (wid >> 1) * 64, wc = (wid & 1) * 64;
    const int fr = lane & 15, fk = (lane >> 4) * 8;

    fl4 acc[4][4];
    #pragma unroll
    for (int i = 0; i < 4; ++i)
        #pragma unroll
        for (int j = 0; j < 4; ++j) acc[i][j] = (fl4){0.f, 0.f, 0.f, 0.f};

    for (int kt = 0; kt < 16; ++kt) {
        const int kb = kt * 64;
        #pragma unroll
        for (int it = 0; it < 4; ++it) {
            const int g = it * 256 + tid;
            const int r = g >> 3, c = (g & 7) << 3;
            const int lofs = __builtin_amdgcn_readfirstlane((it * 256 + wid * 64) * 16);
            gload16(Ab + (size_t)(m0 + r) * DMODEL + kb + c, (char*)Alds + lofs);
            gload16(Bt + (size_t)(n0 + r) * DMODEL + kb + c, (char*)Blds + lofs);
        }
        __syncthreads();
        #pragma unroll
        for (int ks = 0; ks < 2; ++ks) {
            sh8 a[4], bb[4];
            #pragma unroll
            for (int mi = 0; mi < 4; ++mi) a[mi] = *(const sh8*)&Alds[(wr + mi * 16 + fr) * 64 + ks * 32 + fk];
            #pragma unroll
            for (int ni = 0; ni < 4; ++ni) bb[ni] = *(const sh8*)&Blds[(wc + ni * 16 + fr) * 64 + ks * 32 + fk];
            #pragma unroll
            for (int mi = 0; mi < 4; ++mi)
                #pragma unroll
                for (int ni = 0; ni < 4; ++ni) acc[mi][ni] = mfma16(a[mi], bb[ni], acc[mi][ni]);
        }
        __syncthreads();
    }

    #pragma unroll
    for (int mi = 0; mi < 4; ++mi) {
        #pragma unroll
        for (int ni = 0; ni < 4; ++ni) {
            const int col = n0 + wc + ni * 16 + fr;
            const float bv = bias[col] * bscale;
            #pragma unroll
            for (int i = 0; i < 4; ++i) {
                const int row = m0 + wr + mi * 16 + (lane >> 4) * 4 + i;
                float val = acc[mi][ni][i] + bv;
                if (RESID) val += resid[(size_t)row * DMODEL + col];
                if (OUT_BF16) ((uint16_t*)Cv)[(size_t)row * DMODEL + col] = f2bf(val);
                else          ((float*)Cv)[(size_t)row * DMODEL + col] = val;
            }
        }
    }
}

// fused projection GEMM: grid (m=64, n=8, z=3); m fastest => A-panel sharers land on one XCD
__global__ __launch_bounds__(256)
void gemm_proj(const uint16_t* __restrict__ A0, const uint16_t* __restrict__ A1, const uint16_t* __restrict__ A2,
               const uint16_t* __restrict__ B0, const uint16_t* __restrict__ B1, const uint16_t* __restrict__ B2,
               const float* __restrict__ b0, const float* __restrict__ b1, const float* __restrict__ b2,
               uint16_t* __restrict__ C0, uint16_t* __restrict__ C1, uint16_t* __restrict__ C2) {
    __shared__ uint16_t Alds[128 * 64];
    __shared__ uint16_t Blds[128 * 64];
    const int z = blockIdx.z;
    const uint16_t* Ab = (z == 0) ? A0 : (z == 1) ? A1 : A2;
    const uint16_t* Bt = (z == 0) ? B0 : (z == 1) ? B1 : B2;
    const float* bias  = (z == 0) ? b0 : (z == 1) ? b1 : b2;
    uint16_t* Cv       = (z == 0) ? C0 : (z == 1) ? C1 : C2;
    const float bs     = (z == 0) ? 0.125f : 1.f;   // bq folded with the 1/sqrt(dk)
    gemm_body<true, false>(Ab, Bt, bias, bs, nullptr, Cv, blockIdx.x * 128, blockIdx.y * 128, Alds, Blds);
}

// out-proj GEMM: fp32 out + residual; grid (m=64, n=8)
__global__ __launch_bounds__(256)
void gemm_out(const uint16_t* __restrict__ Ab, const uint16_t* __restrict__ Bt,
              const float* __restrict__ bias, const float* __restrict__ resid,
              float* __restrict__ Cv) {
    __shared__ uint16_t Alds[128 * 64];
    __shared__ uint16_t Blds[128 * 64];
    gemm_body<false, true>(Ab, Bt, bias, 1.f, resid, Cv, blockIdx.x * 128, blockIdx.y * 128, Alds, Blds);
}

// ---------------- attention: one block = (b, h, 16 q-rows); S bf16[16][1024] (32KB), XOR-swizzled
// grid (b=8, h=16, qtile=64): batch fastest => each XCD owns one batch's K/V in its L2
__global__ __launch_bounds__(256)
void attn_kernel(const uint16_t* __restrict__ qh, const uint16_t* __restrict__ kh,
                 const uint16_t* __restrict__ vT, const uint8_t* __restrict__ mask,
                 float* __restrict__ attn, uint16_t* __restrict__ ctx) {
    __shared__ uint16_t S[16 * 1024];       // 32 KB
    __shared__ float rinv[16];
    const int b = blockIdx.x, h = blockIdx.y, q0 = blockIdx.z * 16;
    const int tid = threadIdx.x, lane = tid & 63, wid = tid >> 6;
    const int fr = lane & 15, fk = (lane >> 4) * 8, frow4 = (lane >> 4) * 4;

    // Q fragments (16x64 tile, each wave holds full copy); qh is pre-scaled by 0.125
    sh8 Aq[2];
    #pragma unroll
    for (int ks = 0; ks < 2; ++ks)
        Aq[ks] = *(const sh8*)(qh + (size_t)(b * SEQ + q0 + fr) * DMODEL + h * 64 + ks * 32 + fk);

    // phase 1: S = bf16(QK^T); wave wid covers kv tiles {wid, wid+4, ...}
    for (int t8 = 0; t8 < 8; ++t8) {
        const int kv0 = (t8 * 4 + wid) * 32;
        sh8 Bk[2][2];
        #pragma unroll
        for (int ni = 0; ni < 2; ++ni)
            #pragma unroll
            for (int ks = 0; ks < 2; ++ks)
                Bk[ni][ks] = *(const sh8*)(kh + (size_t)(b * SEQ + kv0 + ni * 16 + fr) * DMODEL + h * 64 + ks * 32 + fk);
        fl4 sa[2];
        #pragma unroll
        for (int ni = 0; ni < 2; ++ni) sa[ni] = (fl4){0.f, 0.f, 0.f, 0.f};
        #pragma unroll
        for (int ni = 0; ni < 2; ++ni)
            #pragma unroll
            for (int ks = 0; ks < 2; ++ks) sa[ni] = mfma16(Aq[ks], Bk[ni][ks], sa[ni]);
        #pragma unroll
        for (int ni = 0; ni < 2; ++ni)
            #pragma unroll
            for (int i = 0; i < 4; ++i) {
                const int row = frow4 + i, col = kv0 + ni * 16 + fr;
                S[row * 1024 + ((((col >> 3) ^ (row & 15)) << 3) | (col & 7))] = f2bf(sa[ni][i]);
            }
    }
    __syncthreads();

    // phase 2: register-resident masked softmax; 16 lanes/row, 8 interleaved 16B chunks per lane
    {
        const int r = tid >> 4, j = tid & 15;
        const int rbase = r * 1024;
        const uint8_t* mbase = mask + (size_t)(b * SEQ + q0 + r) * SEQ;
        sh8 x[8];
        uint2 mw[8];
        // pass A: load chunks + mask words; masked max (no writeback)
        float mx = -1e30f;
        #pragma unroll
        for (int c4 = 0; c4 < 8; ++c4) {
            const int cc = c4 * 16 + j;
            x[c4] = *(sh8*)&S[rbase + ((cc ^ r) << 3)];
            mw[c4] = *(const uint2*)(mbase + cc * 8);
            #pragma unroll
            for (int t = 0; t < 4; ++t) {
                float f = ((mw[c4].x >> (t * 8)) & 0xFF) ? -1e9f : b2f((uint16_t)x[c4][t]);
                mx = fmaxf(mx, f);
            }
            #pragma unroll
            for (int t = 0; t < 4; ++t) {
                float f = ((mw[c4].y >> (t * 8)) & 0xFF) ? -1e9f : b2f((uint16_t)x[c4][4 + t]);
                mx = fmaxf(mx, f);
            }
        }
        #pragma unroll
        for (int d = 1; d < 16; d <<= 1) mx = fmaxf(mx, __shfl_xor(mx, d));
        // pass B: exp in regs -> packed bf16 (cvt_pk) -> LDS (for PV), track sum
        float sum = 0.f;
        sh8 sv[8];
        #pragma unroll
        for (int c4 = 0; c4 < 8; ++c4) {
            const int cc = c4 * 16 + j;
            float e[8];
            #pragma unroll
            for (int t = 0; t < 4; ++t) {
                float f = ((mw[c4].x >> (t * 8)) & 0xFF) ? -1e9f : b2f((uint16_t)x[c4][t]);
                e[t] = __expf(f - mx);
            }
            #pragma unroll
            for (int t = 0; t < 4; ++t) {
                float f = ((mw[c4].y >> (t * 8)) & 0xFF) ? -1e9f : b2f((uint16_t)x[c4][4 + t]);
                e[4 + t] = __expf(f - mx);
            }
            union { uint32_t w[4]; sh8 v; } pk;
            pk.w[0] = cvtpk(e[0], e[1]); pk.w[1] = cvtpk(e[2], e[3]);
            pk.w[2] = cvtpk(e[4], e[5]); pk.w[3] = cvtpk(e[6], e[7]);
            sv[c4] = pk.v;
            *(sh8*)&S[rbase + ((cc ^ r) << 3)] = pk.v;
            sum += e[0] + e[1] + e[2] + e[3] + e[4] + e[5] + e[6] + e[7];
        }
        #pragma unroll
        for (int d = 1; d < 16; d <<= 1) sum += __shfl_xor(sum, d);
        const float ri = 1.f / sum;
        if (j == 0) rinv[r] = ri;
        // normalized fp32 attn write straight from regs (nontemporal streaming)
        float* ab = attn + ((size_t)((h * BATCH + b) * SEQ + q0 + r)) * SEQ;
        #pragma unroll
        for (int c4 = 0; c4 < 8; ++c4) {
            const int cc = c4 * 16 + j;
            fl4 o0, o1;
            #pragma unroll
            for (int t = 0; t < 4; ++t) o0[t] = b2f((uint16_t)sv[c4][t]) * ri;
            #pragma unroll
            for (int t = 0; t < 4; ++t) o1[t] = b2f((uint16_t)sv[c4][4 + t]) * ri;
            float* dst = ab + cc * 8;
            __builtin_nontemporal_store(o0, (fl4*)dst);
            __builtin_nontemporal_store(o1, (fl4*)(dst + 4));
        }
    }
    __syncthreads();

    // phase 3: ctx = (P_unnorm V) * rinv ; wave wid owns d-block [wid*16, wid*16+16)
    fl4 acc0 = (fl4){0.f, 0.f, 0.f, 0.f}, acc1 = (fl4){0.f, 0.f, 0.f, 0.f};
    const uint16_t* vbase = vT + (size_t)((b * NHEAD + h) * 64 + wid * 16) * SEQ;
    const int frx = fr & 15;
    #pragma unroll 4
    for (int ks2 = 0; ks2 < 32; ++ks2) {
        const int kv = ks2 * 32;
        sh8 Ap = *(const sh8*)&S[fr * 1024 + ((((kv + fk) >> 3) ^ frx) << 3)];
        sh8 Bv = *(const sh8*)(vbase + (size_t)fr * SEQ + kv + fk);
        if (ks2 & 1) acc1 = mfma16(Ap, Bv, acc1);
        else         acc0 = mfma16(Ap, Bv, acc0);
    }
    #pragma unroll
    for (int i = 0; i < 4; ++i) {
        const int q = frow4 + i;
        const float val = (acc0[i] + acc1[i]) * rinv[q];
        ctx[(size_t)(b * SEQ + q0 + q) * DMODEL + h * 64 + wid * 16 + fr] = f2bf(val);
    }
}

// ---------------- LayerNorm (in-place capable): one block per row
__global__ __launch_bounds__(256)
void ln_kernel(const float* __restrict__ raw, const float* __restrict__ gamma,
               const float* __restrict__ beta, float* __restrict__ out) {
    const int row = blockIdx.x;
    const int tid = threadIdx.x;
    const float* x = raw + (size_t)row * DMODEL;
    fl4 xv = *(const fl4*)(x + tid * 4);
    float s  = xv[0] + xv[1] + xv[2] + xv[3];
    float ss = xv[0] * xv[0] + xv[1] * xv[1] + xv[2] * xv[2] + xv[3] * xv[3];
    #pragma unroll
    for (int d = 1; d < 64; d <<= 1) { s += __shfl_xor(s, d); ss += __shfl_xor(ss, d); }
    __shared__ float sb[4], ssb[4];
    if ((tid & 63) == 0) { sb[tid >> 6] = s; ssb[tid >> 6] = ss; }
    __syncthreads();
    s  = sb[0] + sb[1] + sb[2] + sb[3];
    ss = ssb[0] + ssb[1] + ssb[2] + ssb[3];
    const float mu  = s * (1.f / 1024.f);
    const float var = ss * (1.f / 1024.f) - mu * mu;
    const float rstd = rsqrtf(var + 1e-5f);
    fl4 g  = *(const fl4*)(gamma + tid * 4);
    fl4 be = *(const fl4*)(beta + tid * 4);
    fl4 o;
    #pragma unroll
    for (int j = 0; j < 4; ++j) o[j] = (xv[j] - mu) * rstd * g[j] + be[j];
    *(fl4*)(out + (size_t)row * DMODEL + tid * 4) = o;
}

extern "C" void kernel_launch(void* const* d_in, const int* in_sizes, int n_in,
                              void* d_out, int out_size, void* d_ws, size_t ws_size,
                              hipStream_t stream) {
    (void)in_sizes; (void)n_in; (void)out_size; (void)ws_size;
    const float* q     = (const float*)d_in[0];
    const float* k     = (const float*)d_in[1];
    const float* v     = (const float*)d_in[2];
    const uint8_t* mask = (const uint8_t*)d_in[3];
    const float* wq = (const float*)d_in[4];
    const float* bq = (const float*)d_in[5];
    const float* wk = (const float*)d_in[6];
    const float* bk = (const float*)d_in[7];
    const float* wv = (const float*)d_in[8];
    const float* bv = (const float*)d_in[9];
    const float* wo = (const float*)d_in[10];
    const float* bo = (const float*)d_in[11];
    const float* gamma = (const float*)d_in[12];
    const float* beta  = (const float*)d_in[13];

    float* out  = (float*)d_out;                                   // 8M fp32 (raw out-proj, then LN in-place)
    float* attn = out + (size_t)BATCH * SEQ * DMODEL;              // 128M fp32

    // bf16 copies of q/k/v live in the attn output region (consumed before attn_kernel writes it)
    uint16_t* qcvt = (uint16_t*)(attn);
    uint16_t* kcvt = (uint16_t*)((char*)attn + ((size_t)16 << 20));
    uint16_t* vcvt = (uint16_t*)((char*)attn + ((size_t)32 << 20));

    char* ws = (char*)d_ws;
    uint16_t* qh   = (uint16_t*)(ws);                              // 16 MB
    uint16_t* kh   = (uint16_t*)(ws + ((size_t)16 << 20));         // 16 MB
    uint16_t* vT   = (uint16_t*)(ws + ((size_t)32 << 20));         // 16 MB
    uint16_t* ctx  = (uint16_t*)(ws + ((size_t)48 << 20));         // 16 MB
    uint16_t* wqT  = (uint16_t*)(ws + ((size_t)64 << 20));         // 2 MB each
    uint16_t* wkT  = (uint16_t*)(ws + ((size_t)66 << 20));
    uint16_t* wvT  = (uint16_t*)(ws + ((size_t)68 << 20));
    uint16_t* woT  = (uint16_t*)(ws + ((size_t)70 << 20));
    uint16_t* vtmp = (uint16_t*)(ws + ((size_t)72 << 20));         // 16 MB -> total 88 MB

    dim3 tb(256);
    wtrans_kernel<<<dim3(16, 16, 4), tb, 0, stream>>>(wq, wk, wv, wo, wqT, wkT, wvT, woT);
    cvt3_kernel<<<dim3(2048, 1, 3), tb, 0, stream>>>(q, k, v, qcvt, kcvt, vcvt);

    gemm_proj<<<dim3(64, 8, 3), tb, 0, stream>>>(qcvt, kcvt, vcvt, wqT, wkT, wvT,
                                                 bq, bk, bv, qh, kh, vtmp);

    vtrans_kernel<<<dim3(16, 16, 8), tb, 0, stream>>>(vtmp, vT);

    attn_kernel<<<dim3(BATCH, NHEAD, 64), tb, 0, stream>>>(qh, kh, vT, mask, attn, ctx);

    gemm_out<<<dim3(64, 8), tb, 0, stream>>>(ctx, woT, bo, q, out);

    ln_kernel<<<BATCH * SEQ, tb, 0, stream>>>(out, gamma, beta, out);
}

// Round 7
// 449.107 us; speedup vs baseline: 1.5572x; 1.0137x over previous
//
#include <hip/hip_runtime.h>
#include <stdint.h>

static constexpr int BATCH  = 8;
static constexpr int SEQ    = 1024;
static constexpr int DMODEL = 1024;
static constexpr int NHEAD  = 16;

typedef __attribute__((ext_vector_type(8))) short sh8;
typedef __attribute__((ext_vector_type(4))) float fl4;

__device__ __forceinline__ uint16_t f2bf(float f) {
    union { float f; uint32_t u; } a; a.f = f;
    uint32_t r = a.u + 0x7FFFu + ((a.u >> 16) & 1u);
    return (uint16_t)(r >> 16);
}

__device__ __forceinline__ float b2f(uint16_t u) {
    union { uint32_t u; float f; } a; a.u = ((uint32_t)u) << 16; return a.f;
}

// HW packed fp32->bf16 (RNE)
__device__ __forceinline__ uint32_t cvtpk(float lo, float hi) {
    uint32_t r;
    asm("v_cvt_pk_bf16_f32 %0, %1, %2" : "=v"(r) : "v"(lo), "v"(hi));
    return r;
}

__device__ __forceinline__ sh8 pack_bf8(fl4 x0, fl4 x1) {
    union { uint32_t w[4]; sh8 v; } pk;
    pk.w[0] = cvtpk(x0[0], x0[1]); pk.w[1] = cvtpk(x0[2], x0[3]);
    pk.w[2] = cvtpk(x1[0], x1[1]); pk.w[3] = cvtpk(x1[2], x1[3]);
    return pk.v;
}

__device__ __forceinline__ fl4 mfma16(sh8 a, sh8 b, fl4 c) {
    return __builtin_amdgcn_mfma_f32_16x16x32_bf16(a, b, c, 0, 0, 0);
}

__device__ __forceinline__ void gload16(const void* g, void* l) {
    __builtin_amdgcn_global_load_lds(
        (const __attribute__((address_space(1))) void*)g,
        (__attribute__((address_space(3))) void*)l, 16, 0, 0);
}

// ---------------- fused prep: z 0-3 = weight transpose (+0.125 fold on wq), z 4-6 = q/k/v cvt
__global__ __launch_bounds__(256) void prep_kernel(const float* __restrict__ wq, const float* __restrict__ wk,
                                                   const float* __restrict__ wv, const float* __restrict__ wo,
                                                   uint16_t* __restrict__ tq, uint16_t* __restrict__ tk,
                                                   uint16_t* __restrict__ tv, uint16_t* __restrict__ to,
                                                   const float* __restrict__ q, const float* __restrict__ k,
                                                   const float* __restrict__ v,
                                                   uint16_t* __restrict__ dq, uint16_t* __restrict__ dk,
                                                   uint16_t* __restrict__ dv) {
    __shared__ uint16_t T[64][72];
    const int z = blockIdx.z;
    const int tid = threadIdx.x;
    if (z < 4) {
        const float* w = (z == 0) ? wq : (z == 1) ? wk : (z == 2) ? wv : wo;
        uint16_t* wT = (z == 0) ? tq : (z == 1) ? tk : (z == 2) ? tv : to;
        const float ws = (z == 0) ? 0.125f : 1.f;
        const int n0 = blockIdx.x * 64, k0 = blockIdx.y * 64;
        #pragma unroll
        for (int it = 0; it < 4; ++it) {
            int g = it * 256 + tid;
            int r = g >> 4, c = (g & 15) * 4;
            fl4 x = *(const fl4*)(w + (size_t)(k0 + r) * DMODEL + n0 + c);
            T[r][c + 0] = f2bf(x[0] * ws); T[r][c + 1] = f2bf(x[1] * ws);
            T[r][c + 2] = f2bf(x[2] * ws); T[r][c + 3] = f2bf(x[3] * ws);
        }
        __syncthreads();
        #pragma unroll
        for (int it = 0; it < 4; ++it) {
            int g = it * 256 + tid;
            int r = g >> 4, c = (g & 15) * 4;
            ushort4 o;
            o.x = T[c + 0][r]; o.y = T[c + 1][r]; o.z = T[c + 2][r]; o.w = T[c + 3][r];
            *(ushort4*)(wT + (size_t)(n0 + r) * DMODEL + k0 + c) = o;
        }
    } else {
        const int zz = z - 4;
        const float* src = (zz == 0) ? q : (zz == 1) ? k : v;
        uint16_t* dst = (zz == 0) ? dq : (zz == 1) ? dk : dv;
        const int bid = blockIdx.y * 16 + blockIdx.x;
        #pragma unroll
        for (int it = 0; it < 16; ++it) {
            const size_t i = ((size_t)bid * 4096 + it * 256 + tid) * 8;
            fl4 x0 = *(const fl4*)(src + i), x1 = *(const fl4*)(src + i + 4);
            *(sh8*)(dst + i) = pack_bf8(x0, x1);
        }
    }
}

// ---------------- per-batch 1024x1024 bf16 transpose: vT[b*1024+hd][l] = vh[b*1024+l][hd]
__global__ __launch_bounds__(256) void vtrans_kernel(const uint16_t* __restrict__ vh,
                                                     uint16_t* __restrict__ vT) {
    __shared__ uint16_t T[64][72];
    const int l0 = blockIdx.x * 64, hd0 = blockIdx.y * 64, bb = blockIdx.z;
    const uint16_t* src = vh + (size_t)bb * SEQ * DMODEL;
    uint16_t* dst = vT + (size_t)bb * SEQ * DMODEL;
    const int tid = threadIdx.x;
    #pragma unroll
    for (int it = 0; it < 4; ++it) {
        int g = it * 256 + tid;
        int r = g >> 4, c = (g & 15) * 4;
        ushort4 x = *(const ushort4*)(src + (size_t)(l0 + r) * DMODEL + hd0 + c);
        T[r][c + 0] = x.x; T[r][c + 1] = x.y; T[r][c + 2] = x.z; T[r][c + 3] = x.w;
    }
    __syncthreads();
    #pragma unroll
    for (int it = 0; it < 4; ++it) {
        int g = it * 256 + tid;
        int r = g >> 4, c = (g & 15) * 4;
        ushort4 o;
        o.x = T[c + 0][r]; o.y = T[c + 1][r]; o.z = T[c + 2][r]; o.w = T[c + 3][r];
        *(ushort4*)(dst + (size_t)(hd0 + r) * DMODEL + l0 + c) = o;
    }
}

// ---------------- GEMM core (128x128 tile, BK=64, gload_lds staging, LDS-bounced epilogue)
template<bool OUT_BF16, bool RESID>
__device__ __forceinline__
void gemm_body(const uint16_t* __restrict__ Ab, const uint16_t* __restrict__ Bt,
               const float* __restrict__ bias, float bscale, const float* __restrict__ resid,
               void* __restrict__ Cv, int m0, int n0, uint16_t* lds) {
    uint16_t* Alds = lds;
    uint16_t* Blds = lds + 128 * 64;
    const int tid = threadIdx.x;
    const int lane = tid & 63, wid = tid >> 6;
    const int wr = (wid >> 1) * 64, wc = (wid & 1) * 64;
    const int fr = lane & 15, fk = (lane >> 4) * 8, frow4 = (lane >> 4) * 4;

    fl4 acc[4][4];
    #pragma unroll
    for (int i = 0; i < 4; ++i)
        #pragma unroll
        for (int j = 0; j < 4; ++j) acc[i][j] = (fl4){0.f, 0.f, 0.f, 0.f};

    for (int kt = 0; kt < 16; ++kt) {
        const int kb = kt * 64;
        #pragma unroll
        for (int it = 0; it < 4; ++it) {
            const int g = it * 256 + tid;
            const int r = g >> 3, c = (g & 7) << 3;
            const int lofs = __builtin_amdgcn_readfirstlane((it * 256 + wid * 64) * 16);
            gload16(Ab + (size_t)(m0 + r) * DMODEL + kb + c, (char*)Alds + lofs);
            gload16(Bt + (size_t)(n0 + r) * DMODEL + kb + c, (char*)Blds + lofs);
        }
        __syncthreads();
        #pragma unroll
        for (int ks = 0; ks < 2; ++ks) {
            sh8 a[4], bb[4];
            #pragma unroll
            for (int mi = 0; mi < 4; ++mi) a[mi] = *(const sh8*)&Alds[(wr + mi * 16 + fr) * 64 + ks * 32 + fk];
            #pragma unroll
            for (int ni = 0; ni < 4; ++ni) bb[ni] = *(const sh8*)&Blds[(wc + ni * 16 + fr) * 64 + ks * 32 + fk];
            #pragma unroll
            for (int mi = 0; mi < 4; ++mi)
                #pragma unroll
                for (int ni = 0; ni < 4; ++ni) acc[mi][ni] = mfma16(a[mi], bb[ni], acc[mi][ni]);
        }
        __syncthreads();
    }

    if (OUT_BF16) {
        // stage full 128x128 bf16 C-tile in lds (32 KB), chunk-xor swizzled
        #pragma unroll
        for (int mi = 0; mi < 4; ++mi) {
            #pragma unroll
            for (int ni = 0; ni < 4; ++ni) {
                const int col = wc + ni * 16 + fr;
                const float bv = bias[n0 + col] * bscale;
                #pragma unroll
                for (int i = 0; i < 4; ++i) {
                    const int row = wr + mi * 16 + frow4 + i;
                    lds[row * 128 + ((((col >> 3) ^ (row & 7)) << 3) | (col & 7))] = f2bf(acc[mi][ni][i] + bv);
                }
            }
        }
        __syncthreads();
        #pragma unroll
        for (int it = 0; it < 8; ++it) {
            const int ch = it * 256 + tid;
            const int row = ch >> 4, cc = ch & 15;
            sh8 vv = *(sh8*)&lds[row * 128 + ((cc ^ (row & 7)) << 3)];
            *(sh8*)((uint16_t*)Cv + (size_t)(m0 + row) * DMODEL + n0 + cc * 8) = vv;
        }
    } else {
        // fp32 (+resid): two 64-col halves through 32 KB lds
        float* flds = (float*)lds;
        #pragma unroll
        for (int h2 = 0; h2 < 2; ++h2) {
            if (h2) __syncthreads();
            if (wc == h2 * 64) {
                #pragma unroll
                for (int ni = 0; ni < 4; ++ni) {
                    const int col = wc + ni * 16 + fr;        // global col offset within tile
                    const int ch = col - h2 * 64;             // 0..63
                    const float bv = bias[n0 + col] * bscale;
                    #pragma unroll
                    for (int i = 0; i < 4; ++i) {
                        const int row = wr + (0) * 16 + frow4 + i; (void)row;
                    }
                    #pragma unroll
                    for (int mi = 0; mi < 4; ++mi) {
                        #pragma unroll
                        for (int i = 0; i < 4; ++i) {
                            const int row = wr + mi * 16 + frow4 + i;
                            float val = acc[mi][ni][i] + bv;
                            if (RESID) val += resid[(size_t)(m0 + row) * DMODEL + n0 + col];
                            flds[row * 64 + ((((ch >> 2) ^ (row & 7)) << 2) | (ch & 3))] = val;
                        }
                    }
                }
            }
            __syncthreads();
            #pragma unroll
            for (int it = 0; it < 8; ++it) {
                const int ck = it * 256 + tid;
                const int row = ck >> 4, cc = ck & 15;
                fl4 vv = *(fl4*)&flds[row * 64 + ((cc ^ (row & 7)) << 2)];
                *(fl4*)((float*)Cv + (size_t)(m0 + row) * DMODEL + n0 + h2 * 64 + cc * 4) = vv;
            }
        }
    }
}

__global__ __launch_bounds__(256)
void gemm_proj(const uint16_t* __restrict__ A0, const uint16_t* __restrict__ A1, const uint16_t* __restrict__ A2,
               const uint16_t* __restrict__ B0, const uint16_t* __restrict__ B1, const uint16_t* __restrict__ B2,
               const float* __restrict__ b0, const float* __restrict__ b1, const float* __restrict__ b2,
               uint16_t* __restrict__ C0, uint16_t* __restrict__ C1, uint16_t* __restrict__ C2) {
    __shared__ uint16_t lds[2 * 128 * 64];
    const int z = blockIdx.z;
    const uint16_t* Ab = (z == 0) ? A0 : (z == 1) ? A1 : A2;
    const uint16_t* Bt = (z == 0) ? B0 : (z == 1) ? B1 : B2;
    const float* bias  = (z == 0) ? b0 : (z == 1) ? b1 : b2;
    uint16_t* Cv       = (z == 0) ? C0 : (z == 1) ? C1 : C2;
    const float bs     = (z == 0) ? 0.125f : 1.f;
    gemm_body<true, false>(Ab, Bt, bias, bs, nullptr, Cv, blockIdx.x * 128, blockIdx.y * 128, lds);
}

__global__ __launch_bounds__(256)
void gemm_out(const uint16_t* __restrict__ Ab, const uint16_t* __restrict__ Bt,
              const float* __restrict__ bias, const float* __restrict__ resid,
              float* __restrict__ Cv) {
    __shared__ uint16_t lds[2 * 128 * 64];
    gemm_body<false, true>(Ab, Bt, bias, 1.f, resid, Cv, blockIdx.x * 128, blockIdx.y * 128, lds);
}

// ---------------- attention: block = (b, h, 16 q-rows); S bf16[16][1024] swizzled; coalesced NT attn write
__global__ __launch_bounds__(256)
void attn_kernel(const uint16_t* __restrict__ qh, const uint16_t* __restrict__ kh,
                 const uint16_t* __restrict__ vT, const uint8_t* __restrict__ mask,
                 float* __restrict__ attn, uint16_t* __restrict__ ctx) {
    __shared__ uint16_t S[16 * 1024];       // 32 KB
    __shared__ float rinv[16];
    const int b = blockIdx.x, h = blockIdx.y, q0 = blockIdx.z * 16;
    const int tid = threadIdx.x, lane = tid & 63, wid = tid >> 6;
    const int fr = lane & 15, fk = (lane >> 4) * 8, frow4 = (lane >> 4) * 4;

    sh8 Aq[2];
    #pragma unroll
    for (int ks = 0; ks < 2; ++ks)
        Aq[ks] = *(const sh8*)(qh + (size_t)(b * SEQ + q0 + fr) * DMODEL + h * 64 + ks * 32 + fk);

    // phase 1: S = bf16(QK^T)  (qh pre-scaled by 1/sqrt(dk))
    for (int t8 = 0; t8 < 8; ++t8) {
        const int kv0 = (t8 * 4 + wid) * 32;
        sh8 Bk[2][2];
        #pragma unroll
        for (int ni = 0; ni < 2; ++ni)
            #pragma unroll
            for (int ks = 0; ks < 2; ++ks)
                Bk[ni][ks] = *(const sh8*)(kh + (size_t)(b * SEQ + kv0 + ni * 16 + fr) * DMODEL + h * 64 + ks * 32 + fk);
        fl4 sa[2];
        #pragma unroll
        for (int ni = 0; ni < 2; ++ni) sa[ni] = (fl4){0.f, 0.f, 0.f, 0.f};
        #pragma unroll
        for (int ni = 0; ni < 2; ++ni)
            #pragma unroll
            for (int ks = 0; ks < 2; ++ks) sa[ni] = mfma16(Aq[ks], Bk[ni][ks], sa[ni]);
        #pragma unroll
        for (int ni = 0; ni < 2; ++ni)
            #pragma unroll
            for (int i = 0; i < 4; ++i) {
                const int row = frow4 + i, col = kv0 + ni * 16 + fr;
                S[row * 1024 + ((((col >> 3) ^ (row & 15)) << 3) | (col & 7))] = f2bf(sa[ni][i]);
            }
    }
    __syncthreads();

    // phase 2: register masked softmax; exp (unnormalized, bf16) -> S; rinv per row
    {
        const int r = tid >> 4, j = tid & 15;
        const int rbase = r * 1024;
        const uint8_t* mbase = mask + (size_t)(b * SEQ + q0 + r) * SEQ;
        sh8 x[8];
        uint2 mw[8];
        float mx = -1e30f;
        #pragma unroll
        for (int c4 = 0; c4 < 8; ++c4) {
            const int cc = c4 * 16 + j;
            x[c4] = *(sh8*)&S[rbase + ((cc ^ r) << 3)];
            mw[c4] = *(const uint2*)(mbase + cc * 8);
            #pragma unroll
            for (int t = 0; t < 4; ++t) {
                float f = ((mw[c4].x >> (t * 8)) & 0xFF) ? -1e9f : b2f((uint16_t)x[c4][t]);
                mx = fmaxf(mx, f);
            }
            #pragma unroll
            for (int t = 0; t < 4; ++t) {
                float f = ((mw[c4].y >> (t * 8)) & 0xFF) ? -1e9f : b2f((uint16_t)x[c4][4 + t]);
                mx = fmaxf(mx, f);
            }
        }
        #pragma unroll
        for (int d = 1; d < 16; d <<= 1) mx = fmaxf(mx, __shfl_xor(mx, d));
        float sum = 0.f;
        #pragma unroll
        for (int c4 = 0; c4 < 8; ++c4) {
            const int cc = c4 * 16 + j;
            float e[8];
            #pragma unroll
            for (int t = 0; t < 4; ++t) {
                float f = ((mw[c4].x >> (t * 8)) & 0xFF) ? -1e9f : b2f((uint16_t)x[c4][t]);
                e[t] = __expf(f - mx);
            }
            #pragma unroll
            for (int t = 0; t < 4; ++t) {
                float f = ((mw[c4].y >> (t * 8)) & 0xFF) ? -1e9f : b2f((uint16_t)x[c4][4 + t]);
                e[4 + t] = __expf(f - mx);
            }
            union { uint32_t w[4]; sh8 v; } pk;
            pk.w[0] = cvtpk(e[0], e[1]); pk.w[1] = cvtpk(e[2], e[3]);
            pk.w[2] = cvtpk(e[4], e[5]); pk.w[3] = cvtpk(e[6], e[7]);
            *(sh8*)&S[rbase + ((cc ^ r) << 3)] = pk.v;
            sum += e[0] + e[1] + e[2] + e[3] + e[4] + e[5] + e[6] + e[7];
        }
        #pragma unroll
        for (int d = 1; d < 16; d <<= 1) sum += __shfl_xor(sum, d);
        if (j == 0) rinv[r] = 1.f / sum;
    }
    __syncthreads();

    // phase 3: ctx = (P_unnorm V) * rinv ; wave wid owns d-block [wid*16, wid*16+16)
    fl4 acc0 = (fl4){0.f, 0.f, 0.f, 0.f}, acc1 = (fl4){0.f, 0.f, 0.f, 0.f};
    const uint16_t* vbase = vT + (size_t)((b * NHEAD + h) * 64 + wid * 16) * SEQ;
    #pragma unroll 4
    for (int ks2 = 0; ks2 < 32; ++ks2) {
        const int kv = ks2 * 32;
        sh8 Ap = *(const sh8*)&S[fr * 1024 + ((((kv + fk) >> 3) ^ fr) << 3)];
        sh8 Bv = *(const sh8*)(vbase + (size_t)fr * SEQ + kv + fk);
        if (ks2 & 1) acc1 = mfma16(Ap, Bv, acc1);
        else         acc0 = mfma16(Ap, Bv, acc0);
    }
    #pragma unroll
    for (int i = 0; i < 4; ++i) {
        const int q = frow4 + i;
        const float val = (acc0[i] + acc1[i]) * rinv[q];
        ctx[(size_t)(b * SEQ + q0 + q) * DMODEL + h * 64 + wid * 16 + fr] = f2bf(val);
    }

    // phase 4: attn global write, fully coalesced 16B/lane NT stores
    {
        float* ab = attn + ((size_t)((h * BATCH + b) * SEQ + q0)) * SEQ;
        #pragma unroll
        for (int it = 0; it < 16; ++it) {
            const int ch = it * 256 + tid;          // fl4 chunk over 16 rows x 256
            const int row = ch >> 8, oc = ch & 255;
            const int cc = oc >> 1, half = oc & 1;
            const ushort4 p = *(const ushort4*)&S[row * 1024 + ((cc ^ row) << 3) + half * 4];
            const float ri = rinv[row];
            fl4 o;
            o[0] = b2f(p.x) * ri; o[1] = b2f(p.y) * ri;
            o[2] = b2f(p.z) * ri; o[3] = b2f(p.w) * ri;
            __builtin_nontemporal_store(o, (fl4*)(ab + (size_t)ch * 4));
        }
    }
}

// ---------------- LayerNorm (in-place): one block per row
__global__ __launch_bounds__(256)
void ln_kernel(const float* __restrict__ raw, const float* __restrict__ gamma,
               const float* __restrict__ beta, float* __restrict__ out) {
    const int row = blockIdx.x;
    const int tid = threadIdx.x;
    const float* x = raw + (size_t)row * DMODEL;
    fl4 xv = *(const fl4*)(x + tid * 4);
    float s  = xv[0] + xv[1] + xv[2] + xv[3];
    float ss = xv[0] * xv[0] + xv[1] * xv[1] + xv[2] * xv[2] + xv[3] * xv[3];
    #pragma unroll
    for (int d = 1; d < 64; d <<= 1) { s += __shfl_xor(s, d); ss += __shfl_xor(ss, d); }
    __shared__ float sb[4], ssb[4];
    if ((tid & 63) == 0) { sb[tid >> 6] = s; ssb[tid >> 6] = ss; }
    __syncthreads();
    s  = sb[0] + sb[1] + sb[2] + sb[3];
    ss = ssb[0] + ssb[1] + ssb[2] + ssb[3];
    const float mu  = s * (1.f / 1024.f);
    const float var = ss * (1.f / 1024.f) - mu * mu;
    const float rstd = rsqrtf(var + 1e-5f);
    fl4 g  = *(const fl4*)(gamma + tid * 4);
    fl4 be = *(const fl4*)(beta + tid * 4);
    fl4 o;
    #pragma unroll
    for (int j = 0; j < 4; ++j) o[j] = (xv[j] - mu) * rstd * g[j] + be[j];
    *(fl4*)(out + (size_t)row * DMODEL + tid * 4) = o;
}

extern "C" void kernel_launch(void* const* d_in, const int* in_sizes, int n_in,
                              void* d_out, int out_size, void* d_ws, size_t ws_size,
                              hipStream_t stream) {
    (void)in_sizes; (void)n_in; (void)out_size; (void)ws_size;
    const float* q     = (const float*)d_in[0];
    const float* k     = (const float*)d_in[1];
    const float* v     = (const float*)d_in[2];
    const uint8_t* mask = (const uint8_t*)d_in[3];
    const float* wq = (const float*)d_in[4];
    const float* bq = (const float*)d_in[5];
    const float* wk = (const float*)d_in[6];
    const float* bk = (const float*)d_in[7];
    const float* wv = (const float*)d_in[8];
    const float* bv = (const float*)d_in[9];
    const float* wo = (const float*)d_in[10];
    const float* bo = (const float*)d_in[11];
    const float* gamma = (const float*)d_in[12];
    const float* beta  = (const float*)d_in[13];

    float* out  = (float*)d_out;
    float* attn = out + (size_t)BATCH * SEQ * DMODEL;

    uint16_t* qcvt = (uint16_t*)(attn);
    uint16_t* kcvt = (uint16_t*)((char*)attn + ((size_t)16 << 20));
    uint16_t* vcvt = (uint16_t*)((char*)attn + ((size_t)32 << 20));

    char* ws = (char*)d_ws;
    uint16_t* qh   = (uint16_t*)(ws);
    uint16_t* kh   = (uint16_t*)(ws + ((size_t)16 << 20));
    uint16_t* vT   = (uint16_t*)(ws + ((size_t)32 << 20));
    uint16_t* ctx  = (uint16_t*)(ws + ((size_t)48 << 20));
    uint16_t* wqT  = (uint16_t*)(ws + ((size_t)64 << 20));
    uint16_t* wkT  = (uint16_t*)(ws + ((size_t)66 << 20));
    uint16_t* wvT  = (uint16_t*)(ws + ((size_t)68 << 20));
    uint16_t* woT  = (uint16_t*)(ws + ((size_t)70 << 20));
    uint16_t* vtmp = (uint16_t*)(ws + ((size_t)72 << 20));

    dim3 tb(256);
    prep_kernel<<<dim3(16, 16, 7), tb, 0, stream>>>(wq, wk, wv, wo, wqT, wkT, wvT, woT,
                                                    q, k, v, qcvt, kcvt, vcvt);

    gemm_proj<<<dim3(64, 8, 3), tb, 0, stream>>>(qcvt, kcvt, vcvt, wqT, wkT, wvT,
                                                 bq, bk, bv, qh, kh, vtmp);

    vtrans_kernel<<<dim3(16, 16, 8), tb, 0, stream>>>(vtmp, vT);

    attn_kernel<<<dim3(BATCH, NHEAD, 64), tb, 0, stream>>>(qh, kh, vT, mask, attn, ctx);

    gemm_out<<<dim3(64, 8), tb, 0, stream>>>(ctx, woT, bo, q, out);

    ln_kernel<<<BATCH * SEQ, tb, 0, stream>>>(out, gamma, beta, out);
}

// Round 8
// 415.321 us; speedup vs baseline: 1.6839x; 1.0813x over previous
//
#include <hip/hip_runtime.h>
#include <stdint.h>

static constexpr int BATCH  = 8;
static constexpr int SEQ    = 1024;
static constexpr int DMODEL = 1024;
static constexpr int NHEAD  = 16;

typedef __attribute__((ext_vector_type(8))) short sh8;
typedef __attribute__((ext_vector_type(4))) float fl4;

__device__ __forceinline__ uint16_t f2bf(float f) {
    union { float f; uint32_t u; } a; a.f = f;
    uint32_t r = a.u + 0x7FFFu + ((a.u >> 16) & 1u);
    return (uint16_t)(r >> 16);
}

__device__ __forceinline__ float b2f(uint16_t u) {
    union { uint32_t u; float f; } a; a.u = ((uint32_t)u) << 16; return a.f;
}

// HW packed fp32->bf16 (RNE)
__device__ __forceinline__ uint32_t cvtpk(float lo, float hi) {
    uint32_t r;
    asm("v_cvt_pk_bf16_f32 %0, %1, %2" : "=v"(r) : "v"(lo), "v"(hi));
    return r;
}

__device__ __forceinline__ sh8 pack_bf8(fl4 x0, fl4 x1) {
    union { uint32_t w[4]; sh8 v; } pk;
    pk.w[0] = cvtpk(x0[0], x0[1]); pk.w[1] = cvtpk(x0[2], x0[3]);
    pk.w[2] = cvtpk(x1[0], x1[1]); pk.w[3] = cvtpk(x1[2], x1[3]);
    return pk.v;
}

__device__ __forceinline__ fl4 mfma16(sh8 a, sh8 b, fl4 c) {
    return __builtin_amdgcn_mfma_f32_16x16x32_bf16(a, b, c, 0, 0, 0);
}

__device__ __forceinline__ void gload16(const void* g, void* l) {
    __builtin_amdgcn_global_load_lds(
        (const __attribute__((address_space(1))) void*)g,
        (__attribute__((address_space(3))) void*)l, 16, 0, 0);
}

// ---------------- weight transpose + fp32->bf16 (0.125 fold on wq): wT[n][k] = w[k][n]
__global__ __launch_bounds__(256) void prep_kernel(const float* __restrict__ wq, const float* __restrict__ wk,
                                                   const float* __restrict__ wv, const float* __restrict__ wo,
                                                   uint16_t* __restrict__ tq, uint16_t* __restrict__ tk,
                                                   uint16_t* __restrict__ tv, uint16_t* __restrict__ to) {
    __shared__ uint16_t T[64][72];
    const int z = blockIdx.z;
    const int tid = threadIdx.x;
    const float* w = (z == 0) ? wq : (z == 1) ? wk : (z == 2) ? wv : wo;
    uint16_t* wT = (z == 0) ? tq : (z == 1) ? tk : (z == 2) ? tv : to;
    const float ws = (z == 0) ? 0.125f : 1.f;
    const int n0 = blockIdx.x * 64, k0 = blockIdx.y * 64;
    #pragma unroll
    for (int it = 0; it < 4; ++it) {
        int g = it * 256 + tid;
        int r = g >> 4, c = (g & 15) * 4;
        fl4 x = *(const fl4*)(w + (size_t)(k0 + r) * DMODEL + n0 + c);
        T[r][c + 0] = f2bf(x[0] * ws); T[r][c + 1] = f2bf(x[1] * ws);
        T[r][c + 2] = f2bf(x[2] * ws); T[r][c + 3] = f2bf(x[3] * ws);
    }
    __syncthreads();
    #pragma unroll
    for (int it = 0; it < 4; ++it) {
        int g = it * 256 + tid;
        int r = g >> 4, c = (g & 15) * 4;
        ushort4 o;
        o.x = T[c + 0][r]; o.y = T[c + 1][r]; o.z = T[c + 2][r]; o.w = T[c + 3][r];
        *(ushort4*)(wT + (size_t)(n0 + r) * DMODEL + k0 + c) = o;
    }
}

// ---------------- projection GEMM with fused fp32->bf16 A-staging; z=2 writes V transposed
// grid (m=64, n=8, z=3)
__global__ __launch_bounds__(256)
void gemm_proj(const float* __restrict__ q, const float* __restrict__ k, const float* __restrict__ v,
               const uint16_t* __restrict__ B0, const uint16_t* __restrict__ B1, const uint16_t* __restrict__ B2,
               const float* __restrict__ b0, const float* __restrict__ b1, const float* __restrict__ b2,
               uint16_t* __restrict__ qh, uint16_t* __restrict__ kh, uint16_t* __restrict__ vT) {
    __shared__ uint16_t lds[128 * 128];     // 32 KB: A|B staging, then epilogue C-tile
    uint16_t* Alds = lds;
    uint16_t* Blds = lds + 128 * 64;
    const int z = blockIdx.z;
    const float* Af    = (z == 0) ? q : (z == 1) ? k : v;
    const uint16_t* Bt = (z == 0) ? B0 : (z == 1) ? B1 : B2;
    const float* bias  = (z == 0) ? b0 : (z == 1) ? b1 : b2;
    const float bs     = (z == 0) ? 0.125f : 1.f;
    const int m0 = blockIdx.x * 128, n0 = blockIdx.y * 128;
    const int tid = threadIdx.x, lane = tid & 63, wid = tid >> 6;
    const int wr = (wid >> 1) * 64, wc = (wid & 1) * 64;
    const int fr = lane & 15, fk = (lane >> 4) * 8, frow4 = (lane >> 4) * 4;

    fl4 acc[4][4];
    #pragma unroll
    for (int i = 0; i < 4; ++i)
        #pragma unroll
        for (int j = 0; j < 4; ++j) acc[i][j] = (fl4){0.f, 0.f, 0.f, 0.f};

    for (int kt = 0; kt < 16; ++kt) {
        const int kb = kt * 64;
        #pragma unroll
        for (int it = 0; it < 4; ++it) {
            const int g = it * 256 + tid;
            const int r = g >> 3, c = (g & 7) << 3;
            // A: fp32 load + cvt + ds_write (fused conversion)
            const float* p = Af + (size_t)(m0 + r) * DMODEL + kb + c;
            fl4 x0 = *(const fl4*)p, x1 = *(const fl4*)(p + 4);
            *(sh8*)&Alds[r * 64 + c] = pack_bf8(x0, x1);
            // B: async global->LDS
            const int lofs = __builtin_amdgcn_readfirstlane((it * 256 + wid * 64) * 16);
            gload16(Bt + (size_t)(n0 + r) * DMODEL + kb + c, (char*)Blds + lofs);
        }
        __syncthreads();
        #pragma unroll
        for (int ks = 0; ks < 2; ++ks) {
            sh8 a[4], bb[4];
            #pragma unroll
            for (int mi = 0; mi < 4; ++mi) a[mi] = *(const sh8*)&Alds[(wr + mi * 16 + fr) * 64 + ks * 32 + fk];
            #pragma unroll
            for (int ni = 0; ni < 4; ++ni) bb[ni] = *(const sh8*)&Blds[(wc + ni * 16 + fr) * 64 + ks * 32 + fk];
            #pragma unroll
            for (int mi = 0; mi < 4; ++mi)
                #pragma unroll
                for (int ni = 0; ni < 4; ++ni) acc[mi][ni] = mfma16(a[mi], bb[ni], acc[mi][ni]);
        }
        __syncthreads();
    }

    if (z < 2) {
        // normal layout: stage 128x128 bf16 tile (chunk-xor swizzle), drain coalesced
        #pragma unroll
        for (int mi = 0; mi < 4; ++mi) {
            #pragma unroll
            for (int ni = 0; ni < 4; ++ni) {
                const int col = wc + ni * 16 + fr;
                const float bv = bias[n0 + col] * bs;
                #pragma unroll
                for (int i = 0; i < 4; ++i) {
                    const int row = wr + mi * 16 + frow4 + i;
                    lds[row * 128 + ((((col >> 3) ^ (row & 7)) << 3) | (col & 7))] = f2bf(acc[mi][ni][i] + bv);
                }
            }
        }
        __syncthreads();
        uint16_t* Cv = (z == 0) ? qh : kh;
        #pragma unroll
        for (int it = 0; it < 8; ++it) {
            const int ch = it * 256 + tid;
            const int row = ch >> 4, cc = ch & 15;
            sh8 vv = *(sh8*)&lds[row * 128 + ((cc ^ (row & 7)) << 3)];
            *(sh8*)(Cv + (size_t)(m0 + row) * DMODEL + n0 + cc * 8) = vv;
        }
    } else {
        // transposed: stage tile as ldsT[col][row] (row-chunk xor swizzle), write to vT[b*1024+hd][l]
        #pragma unroll
        for (int mi = 0; mi < 4; ++mi) {
            #pragma unroll
            for (int ni = 0; ni < 4; ++ni) {
                const int col = wc + ni * 16 + fr;
                const float bv = bias[n0 + col];
                #pragma unroll
                for (int i = 0; i < 4; ++i) {
                    const int row = wr + mi * 16 + frow4 + i;
                    lds[col * 128 + ((((row >> 3) ^ (col & 7)) << 3) | (row & 7))] = f2bf(acc[mi][ni][i] + bv);
                }
            }
        }
        __syncthreads();
        const int b = m0 >> 10, l0 = m0 & 1023;
        #pragma unroll
        for (int it = 0; it < 8; ++it) {
            const int ch = it * 256 + tid;
            const int col = ch >> 4, rc = ch & 15;
            sh8 vv = *(sh8*)&lds[col * 128 + ((rc ^ (col & 7)) << 3)];
            *(sh8*)(vT + (size_t)(b * 1024 + n0 + col) * SEQ + l0 + rc * 8) = vv;
        }
    }
}

// ---------------- out-proj GEMM: bf16 A (ctx) via gload_lds, fp32 out + residual; grid (64, 8)
__global__ __launch_bounds__(256)
void gemm_out(const uint16_t* __restrict__ Ab, const uint16_t* __restrict__ Bt,
              const float* __restrict__ bias, const float* __restrict__ resid,
              float* __restrict__ Cv) {
    __shared__ uint16_t lds[128 * 128];
    uint16_t* Alds = lds;
    uint16_t* Blds = lds + 128 * 64;
    const int m0 = blockIdx.x * 128, n0 = blockIdx.y * 128;
    const int tid = threadIdx.x, lane = tid & 63, wid = tid >> 6;
    const int wr = (wid >> 1) * 64, wc = (wid & 1) * 64;
    const int fr = lane & 15, fk = (lane >> 4) * 8, frow4 = (lane >> 4) * 4;

    fl4 acc[4][4];
    #pragma unroll
    for (int i = 0; i < 4; ++i)
        #pragma unroll
        for (int j = 0; j < 4; ++j) acc[i][j] = (fl4){0.f, 0.f, 0.f, 0.f};

    for (int kt = 0; kt < 16; ++kt) {
        const int kb = kt * 64;
        #pragma unroll
        for (int it = 0; it < 4; ++it) {
            const int g = it * 256 + tid;
            const int r = g >> 3, c = (g & 7) << 3;
            const int lofs = __builtin_amdgcn_readfirstlane((it * 256 + wid * 64) * 16);
            gload16(Ab + (size_t)(m0 + r) * DMODEL + kb + c, (char*)Alds + lofs);
            gload16(Bt + (size_t)(n0 + r) * DMODEL + kb + c, (char*)Blds + lofs);
        }
        __syncthreads();
        #pragma unroll
        for (int ks = 0; ks < 2; ++ks) {
            sh8 a[4], bb[4];
            #pragma unroll
            for (int mi = 0; mi < 4; ++mi) a[mi] = *(const sh8*)&Alds[(wr + mi * 16 + fr) * 64 + ks * 32 + fk];
            #pragma unroll
            for (int ni = 0; ni < 4; ++ni) bb[ni] = *(const sh8*)&Blds[(wc + ni * 16 + fr) * 64 + ks * 32 + fk];
            #pragma unroll
            for (int mi = 0; mi < 4; ++mi)
                #pragma unroll
                for (int ni = 0; ni < 4; ++ni) acc[mi][ni] = mfma16(a[mi], bb[ni], acc[mi][ni]);
        }
        __syncthreads();
    }

    // fp32 (+resid): two 64-col halves through 32 KB lds
    float* flds = (float*)lds;
    #pragma unroll
    for (int h2 = 0; h2 < 2; ++h2) {
        if (h2) __syncthreads();
        if (wc == h2 * 64) {
            #pragma unroll
            for (int ni = 0; ni < 4; ++ni) {
                const int col = wc + ni * 16 + fr;
                const int ch = col - h2 * 64;
                const float bv = bias[n0 + col];
                #pragma unroll
                for (int mi = 0; mi < 4; ++mi) {
                    #pragma unroll
                    for (int i = 0; i < 4; ++i) {
                        const int row = wr + mi * 16 + frow4 + i;
                        float val = acc[mi][ni][i] + bv;
                        val += resid[(size_t)(m0 + row) * DMODEL + n0 + col];
                        flds[row * 64 + ((((ch >> 2) ^ (row & 7)) << 2) | (ch & 3))] = val;
                    }
                }
            }
        }
        __syncthreads();
        #pragma unroll
        for (int it = 0; it < 8; ++it) {
            const int ck = it * 256 + tid;
            const int row = ck >> 4, cc = ck & 15;
            fl4 vv = *(fl4*)&flds[row * 64 + ((cc ^ (row & 7)) << 2)];
            *(fl4*)(Cv + (size_t)(m0 + row) * DMODEL + n0 + h2 * 64 + cc * 4) = vv;
        }
    }
}

// ---------------- attention: block = (b, h, 16 q-rows); S bf16[16][1024] swizzled
__global__ __launch_bounds__(256)
void attn_kernel(const uint16_t* __restrict__ qh, const uint16_t* __restrict__ kh,
                 const uint16_t* __restrict__ vT, const uint8_t* __restrict__ mask,
                 float* __restrict__ attn, uint16_t* __restrict__ ctx) {
    __shared__ uint16_t S[16 * 1024];       // 32 KB
    __shared__ float rinv[16];
    const int b = blockIdx.x, h = blockIdx.y, q0 = blockIdx.z * 16;
    const int tid = threadIdx.x, lane = tid & 63, wid = tid >> 6;
    const int fr = lane & 15, fk = (lane >> 4) * 8, frow4 = (lane >> 4) * 4;

    sh8 Aq[2];
    #pragma unroll
    for (int ks = 0; ks < 2; ++ks)
        Aq[ks] = *(const sh8*)(qh + (size_t)(b * SEQ + q0 + fr) * DMODEL + h * 64 + ks * 32 + fk);

    // phase 1: S = bf16(QK^T)  (qh pre-scaled by 1/sqrt(dk))
    for (int t8 = 0; t8 < 8; ++t8) {
        const int kv0 = (t8 * 4 + wid) * 32;
        sh8 Bk[2][2];
        #pragma unroll
        for (int ni = 0; ni < 2; ++ni)
            #pragma unroll
            for (int ks = 0; ks < 2; ++ks)
                Bk[ni][ks] = *(const sh8*)(kh + (size_t)(b * SEQ + kv0 + ni * 16 + fr) * DMODEL + h * 64 + ks * 32 + fk);
        fl4 sa[2];
        #pragma unroll
        for (int ni = 0; ni < 2; ++ni) sa[ni] = (fl4){0.f, 0.f, 0.f, 0.f};
        #pragma unroll
        for (int ni = 0; ni < 2; ++ni)
            #pragma unroll
            for (int ks = 0; ks < 2; ++ks) sa[ni] = mfma16(Aq[ks], Bk[ni][ks], sa[ni]);
        #pragma unroll
        for (int ni = 0; ni < 2; ++ni)
            #pragma unroll
            for (int i = 0; i < 4; ++i) {
                const int row = frow4 + i, col = kv0 + ni * 16 + fr;
                S[row * 1024 + ((((col >> 3) ^ (row & 15)) << 3) | (col & 7))] = f2bf(sa[ni][i]);
            }
    }
    __syncthreads();

    // phase 2: register masked softmax; exp (unnormalized, bf16) -> S; rinv per row
    {
        const int r = tid >> 4, j = tid & 15;
        const int rbase = r * 1024;
        const uint8_t* mbase = mask + (size_t)(b * SEQ + q0 + r) * SEQ;
        sh8 x[8];
        uint2 mw[8];
        float mx = -1e30f;
        #pragma unroll
        for (int c4 = 0; c4 < 8; ++c4) {
            const int cc = c4 * 16 + j;
            x[c4] = *(sh8*)&S[rbase + ((cc ^ r) << 3)];
            mw[c4] = *(const uint2*)(mbase + cc * 8);
            #pragma unroll
            for (int t = 0; t < 4; ++t) {
                float f = ((mw[c4].x >> (t * 8)) & 0xFF) ? -1e9f : b2f((uint16_t)x[c4][t]);
                mx = fmaxf(mx, f);
            }
            #pragma unroll
            for (int t = 0; t < 4; ++t) {
                float f = ((mw[c4].y >> (t * 8)) & 0xFF) ? -1e9f : b2f((uint16_t)x[c4][4 + t]);
                mx = fmaxf(mx, f);
            }
        }
        #pragma unroll
        for (int d = 1; d < 16; d <<= 1) mx = fmaxf(mx, __shfl_xor(mx, d));
        float sum = 0.f;
        #pragma unroll
        for (int c4 = 0; c4 < 8; ++c4) {
            const int cc = c4 * 16 + j;
            float e[8];
            #pragma unroll
            for (int t = 0; t < 4; ++t) {
                float f = ((mw[c4].x >> (t * 8)) & 0xFF) ? -1e9f : b2f((uint16_t)x[c4][t]);
                e[t] = __expf(f - mx);
            }
            #pragma unroll
            for (int t = 0; t < 4; ++t) {
                float f = ((mw[c4].y >> (t * 8)) & 0xFF) ? -1e9f : b2f((uint16_t)x[c4][4 + t]);
                e[4 + t] = __expf(f - mx);
            }
            union { uint32_t w[4]; sh8 v; } pk;
            pk.w[0] = cvtpk(e[0], e[1]); pk.w[1] = cvtpk(e[2], e[3]);
            pk.w[2] = cvtpk(e[4], e[5]); pk.w[3] = cvtpk(e[6], e[7]);
            *(sh8*)&S[rbase + ((cc ^ r) << 3)] = pk.v;
            sum += e[0] + e[1] + e[2] + e[3] + e[4] + e[5] + e[6] + e[7];
        }
        #pragma unroll
        for (int d = 1; d < 16; d <<= 1) sum += __shfl_xor(sum, d);
        if (j == 0) rinv[r] = 1.f / sum;
    }
    __syncthreads();

    // phase 3a: attn global write first (NT stores drain under the PV compute below)
    {
        float* ab = attn + ((size_t)((h * BATCH + b) * SEQ + q0)) * SEQ;
        #pragma unroll
        for (int it = 0; it < 16; ++it) {
            const int ch = it * 256 + tid;          // fl4 chunk over 16 rows x 256
            const int row = ch >> 8, oc = ch & 255;
            const int cc = oc >> 1, half = oc & 1;
            const ushort4 p = *(const ushort4*)&S[row * 1024 + ((cc ^ row) << 3) + half * 4];
            const float ri = rinv[row];
            fl4 o;
            o[0] = b2f(p.x) * ri; o[1] = b2f(p.y) * ri;
            o[2] = b2f(p.z) * ri; o[3] = b2f(p.w) * ri;
            __builtin_nontemporal_store(o, (fl4*)(ab + (size_t)ch * 4));
        }
    }

    // phase 3b: ctx = (P_unnorm V) * rinv ; wave wid owns d-block [wid*16, wid*16+16)
    fl4 acc0 = (fl4){0.f, 0.f, 0.f, 0.f}, acc1 = (fl4){0.f, 0.f, 0.f, 0.f};
    const uint16_t* vbase = vT + (size_t)((b * NHEAD + h) * 64 + wid * 16) * SEQ;
    #pragma unroll 4
    for (int ks2 = 0; ks2 < 32; ++ks2) {
        const int kv = ks2 * 32;
        sh8 Ap = *(const sh8*)&S[fr * 1024 + ((((kv + fk) >> 3) ^ fr) << 3)];
        sh8 Bv = *(const sh8*)(vbase + (size_t)fr * SEQ + kv + fk);
        if (ks2 & 1) acc1 = mfma16(Ap, Bv, acc1);
        else         acc0 = mfma16(Ap, Bv, acc0);
    }
    __syncthreads();   // all PV reads of S complete before ctx staging overwrites it

    // phase 4: ctx via 2 KB LDS bounce -> coalesced 8B/lane stores
    {
        uint16_t* Sc = S;
        #pragma unroll
        for (int i = 0; i < 4; ++i) {
            const int qr = frow4 + i;
            Sc[qr * 64 + wid * 16 + fr] = f2bf((acc0[i] + acc1[i]) * rinv[qr]);
        }
        __syncthreads();
        const int row = tid >> 4, c4 = (tid & 15) * 4;
        ushort4 vv = *(ushort4*)&Sc[row * 64 + c4];
        *(ushort4*)(ctx + (size_t)(b * SEQ + q0 + row) * DMODEL + h * 64 + c4) = vv;
    }
}

// ---------------- LayerNorm (in-place): one block per row
__global__ __launch_bounds__(256)
void ln_kernel(const float* __restrict__ raw, const float* __restrict__ gamma,
               const float* __restrict__ beta, float* __restrict__ out) {
    const int row = blockIdx.x;
    const int tid = threadIdx.x;
    const float* x = raw + (size_t)row * DMODEL;
    fl4 xv = *(const fl4*)(x + tid * 4);
    float s  = xv[0] + xv[1] + xv[2] + xv[3];
    float ss = xv[0] * xv[0] + xv[1] * xv[1] + xv[2] * xv[2] + xv[3] * xv[3];
    #pragma unroll
    for (int d = 1; d < 64; d <<= 1) { s += __shfl_xor(s, d); ss += __shfl_xor(ss, d); }
    __shared__ float sb[4], ssb[4];
    if ((tid & 63) == 0) { sb[tid >> 6] = s; ssb[tid >> 6] = ss; }
    __syncthreads();
    s  = sb[0] + sb[1] + sb[2] + sb[3];
    ss = ssb[0] + ssb[1] + ssb[2] + ssb[3];
    const float mu  = s * (1.f / 1024.f);
    const float var = ss * (1.f / 1024.f) - mu * mu;
    const float rstd = rsqrtf(var + 1e-5f);
    fl4 g  = *(const fl4*)(gamma + tid * 4);
    fl4 be = *(const fl4*)(beta + tid * 4);
    fl4 o;
    #pragma unroll
    for (int j = 0; j < 4; ++j) o[j] = (xv[j] - mu) * rstd * g[j] + be[j];
    *(fl4*)(out + (size_t)row * DMODEL + tid * 4) = o;
}

extern "C" void kernel_launch(void* const* d_in, const int* in_sizes, int n_in,
                              void* d_out, int out_size, void* d_ws, size_t ws_size,
                              hipStream_t stream) {
    (void)in_sizes; (void)n_in; (void)out_size; (void)ws_size;
    const float* q     = (const float*)d_in[0];
    const float* k     = (const float*)d_in[1];
    const float* v     = (const float*)d_in[2];
    const uint8_t* mask = (const uint8_t*)d_in[3];
    const float* wq = (const float*)d_in[4];
    const float* bq = (const float*)d_in[5];
    const float* wk = (const float*)d_in[6];
    const float* bk = (const float*)d_in[7];
    const float* wv = (const float*)d_in[8];
    const float* bv = (const float*)d_in[9];
    const float* wo = (const float*)d_in[10];
    const float* bo = (const float*)d_in[11];
    const float* gamma = (const float*)d_in[12];
    const float* beta  = (const float*)d_in[13];

    float* out  = (float*)d_out;
    float* attn = out + (size_t)BATCH * SEQ * DMODEL;

    char* ws = (char*)d_ws;
    uint16_t* qh   = (uint16_t*)(ws);
    uint16_t* kh   = (uint16_t*)(ws + ((size_t)16 << 20));
    uint16_t* vT   = (uint16_t*)(ws + ((size_t)32 << 20));
    uint16_t* ctx  = (uint16_t*)(ws + ((size_t)48 << 20));
    uint16_t* wqT  = (uint16_t*)(ws + ((size_t)64 << 20));
    uint16_t* wkT  = (uint16_t*)(ws + ((size_t)66 << 20));
    uint16_t* wvT  = (uint16_t*)(ws + ((size_t)68 << 20));
    uint16_t* woT  = (uint16_t*)(ws + ((size_t)70 << 20));

    dim3 tb(256);
    prep_kernel<<<dim3(16, 16, 4), tb, 0, stream>>>(wq, wk, wv, wo, wqT, wkT, wvT, woT);

    gemm_proj<<<dim3(64, 8, 3), tb, 0, stream>>>(q, k, v, wqT, wkT, wvT,
                                                 bq, bk, bv, qh, kh, vT);

    attn_kernel<<<dim3(BATCH, NHEAD, 64), tb, 0, stream>>>(qh, kh, vT, mask, attn, ctx);

    gemm_out<<<dim3(64, 8), tb, 0, stream>>>(ctx, woT, bo, q, out);

    ln_kernel<<<BATCH * SEQ, tb, 0, stream>>>(out, gamma, beta, out);
}